// Round 1
// baseline (2762.281 us; speedup 1.0000x reference)
//
#include <hip/hip_runtime.h>
#include <math.h>

#define NB 4
#define LIN 40960
#define NC 512
#define T0 8192
#define T1 2048
#define T2 1024
#define T3 512
#define TN 256
#define DM 2048
#define EPSF 1e-5f
#define TEMPF 1e-5f

// Block-wide sum of two values across 512 threads (8 waves). All threads get result.
__device__ __forceinline__ void blk_sum2_512(float& a, float& b, float* scratch /*16 floats*/) {
#pragma unroll
  for (int off = 32; off > 0; off >>= 1) {
    a += __shfl_down(a, off, 64);
    b += __shfl_down(b, off, 64);
  }
  int lane = threadIdx.x & 63, wid = threadIdx.x >> 6;
  __syncthreads();  // protect scratch from previous call
  if (lane == 0) { scratch[wid] = a; scratch[8 + wid] = b; }
  __syncthreads();
  float sa = 0.f, sb = 0.f;
#pragma unroll
  for (int i = 0; i < 8; i++) { sa += scratch[i]; sb += scratch[8 + i]; }
  a = sa; b = sb;
}

// conv0 (Cin=1, K=10, S=5, pad=3 reflect) + ChannelNorm + ReLU. grid NB*T0, block 512.
__global__ __launch_bounds__(512) void k_conv0(const float* __restrict__ x, const float* __restrict__ w,
                                               const float* __restrict__ bias, const float* __restrict__ gw,
                                               const float* __restrict__ gb, float* __restrict__ out) {
  __shared__ float xv[10];
  __shared__ float red[16];
  int b = blockIdx.x / T0, t = blockIdx.x % T0;
  int tid = threadIdx.x;
  if (tid < 10) {
    int gt = t * 5 - 3 + tid;
    if (gt < 0) gt = -gt;
    if (gt >= LIN) gt = 2 * LIN - 2 - gt;
    xv[tid] = x[(size_t)b * LIN + gt];
  }
  __syncthreads();
  float acc = bias[tid];
#pragma unroll
  for (int k = 0; k < 10; k++) acc += xv[k] * w[tid * 10 + k];
  float s = acc, q = acc * acc;
  blk_sum2_512(s, q, red);
  float mean = s * (1.f / NC);
  float var = fmaxf((q - s * s * (1.f / NC)) * (1.f / (NC - 1)), 0.f);
  float y = (acc - mean) * rsqrtf(var + EPSF) * gw[tid] + gb[tid];
  out[((size_t)b * T0 + t) * NC + tid] = fmaxf(y, 0.f);
}

// Generic conv (Cin=Cout=512) + ChannelNorm + ReLU, reflect pad.
// Input/output layout [B][T][C]. One block = (b, TG output timesteps), 512 threads = out channels.
template <int TIN, int TOUT, int K, int STRIDE, int PADL, int TG, int NFP>
__global__ __launch_bounds__(512) void k_conv(const float* __restrict__ in, const float* __restrict__ w,
                                              const float* __restrict__ bias, const float* __restrict__ gw,
                                              const float* __restrict__ gb, float* __restrict__ out) {
  constexpr int NF = (TG - 1) * STRIDE + K;
  static_assert(NFP >= NF && (NFP % 4) == 0, "pad");
  __shared__ __align__(16) float sm[NC][NFP];  // transposed frames: sm[ci][f]
  __shared__ float red[16];
  int b = blockIdx.x / (TOUT / TG);
  int t0 = (blockIdx.x % (TOUT / TG)) * TG;
  int tid = threadIdx.x;
  const float* inb = in + (size_t)b * TIN * NC;
  for (int idx = tid; idx < NF * NC; idx += 512) {
    int f = idx / NC, ci = idx - f * NC;  // consecutive tid -> consecutive ci (coalesced)
    int gt = t0 * STRIDE - PADL + f;
    if (gt < 0) gt = -gt;
    if (gt >= TIN) gt = 2 * TIN - 2 - gt;
    sm[ci][f] = inb[(size_t)gt * NC + ci];
  }
  __syncthreads();
  int co = tid;
  float acc[TG];
#pragma unroll
  for (int tt = 0; tt < TG; tt++) acc[tt] = bias[co];
  const float* wr = w + (size_t)co * NC * K;  // contiguous per-thread weight stream
  for (int ci = 0; ci < NC; ci++) {
    float wk[K];
#pragma unroll
    for (int k4 = 0; k4 < K / 4; k4++) {
      float4 wv = reinterpret_cast<const float4*>(wr + ci * K)[k4];
      wk[k4 * 4 + 0] = wv.x; wk[k4 * 4 + 1] = wv.y; wk[k4 * 4 + 2] = wv.z; wk[k4 * 4 + 3] = wv.w;
    }
    float fr[NFP];
#pragma unroll
    for (int f4 = 0; f4 < NFP / 4; f4++) {  // broadcast b128 reads (same addr all lanes)
      float4 v = reinterpret_cast<const float4*>(&sm[ci][0])[f4];
      fr[f4 * 4 + 0] = v.x; fr[f4 * 4 + 1] = v.y; fr[f4 * 4 + 2] = v.z; fr[f4 * 4 + 3] = v.w;
    }
#pragma unroll
    for (int tt = 0; tt < TG; tt++)
#pragma unroll
      for (int k = 0; k < K; k++)
        acc[tt] += fr[tt * STRIDE + k] * wk[k];
  }
#pragma unroll
  for (int tt = 0; tt < TG; tt++) {
    float s = acc[tt], q = acc[tt] * acc[tt];
    blk_sum2_512(s, q, red);
    float mean = s * (1.f / NC);
    float var = fmaxf((q - s * s * (1.f / NC)) * (1.f / (NC - 1)), 0.f);
    float y = (acc[tt] - mean) * rsqrtf(var + EPSF) * gw[co] + gb[co];
    out[((size_t)b * TOUT + t0 + tt) * NC + co] = fmaxf(y, 0.f);
  }
}

// Row-major GEMM: out[r][co] = act(in[r][:] @ w[:, co] + bias[co]); DOUT = 2048.
// Block = 8 rows, 512 threads x 4 cols each.
template <int DIN, bool ACT>
__global__ __launch_bounds__(512) void k_mlp(const float* __restrict__ in, const float* __restrict__ w,
                                             const float* __restrict__ bias, float* __restrict__ out) {
  constexpr int TG = 8;
  __shared__ float sin_[TG][DIN];
  int r0 = blockIdx.x * TG;
  int tid = threadIdx.x;
  for (int idx = tid; idx < TG * DIN; idx += 512) {
    int r = idx / DIN, ci = idx - r * DIN;
    sin_[r][ci] = in[(size_t)(r0 + r) * DIN + ci];
  }
  __syncthreads();
  float acc[TG][4];
#pragma unroll
  for (int r = 0; r < TG; r++)
#pragma unroll
    for (int j = 0; j < 4; j++) acc[r][j] = 0.f;
  for (int ci = 0; ci < DIN; ci++) {
    const float* wrow = w + (size_t)ci * DM + tid;
    float w0 = wrow[0], w1 = wrow[512], w2 = wrow[1024], w3 = wrow[1536];
#pragma unroll
    for (int r = 0; r < TG; r++) {
      float v = sin_[r][ci];
      acc[r][0] += v * w0; acc[r][1] += v * w1; acc[r][2] += v * w2; acc[r][3] += v * w3;
    }
  }
#pragma unroll
  for (int r = 0; r < TG; r++)
#pragma unroll
    for (int j = 0; j < 4; j++) {
      int co = tid + j * 512;
      float v = acc[r][j] + bias[co];
      if (ACT) v = 0.5f * v * (1.f + erff(v * 0.70710678118654752f));  // exact GELU
      out[(size_t)(r0 + r) * DM + co] = v;
    }
}

// Head: imp[row] = sigmoid(z2[row,:] @ w3 + b3) + TEMP. grid NB*T3, block 256.
__global__ __launch_bounds__(256) void k_head(const float* __restrict__ z, const float* __restrict__ w,
                                              const float* __restrict__ bias, float* __restrict__ imp) {
  __shared__ float red[4];
  int row = blockIdx.x, tid = threadIdx.x;
  float a = 0.f;
  for (int i = tid; i < DM; i += 256) a += z[(size_t)row * DM + i] * w[i];
#pragma unroll
  for (int off = 32; off > 0; off >>= 1) a += __shfl_down(a, off, 64);
  int lane = tid & 63, wid = tid >> 6;
  if (lane == 0) red[wid] = a;
  __syncthreads();
  if (tid == 0) {
    float s = red[0] + red[1] + red[2] + red[3] + bias[0];
    imp[row] = 1.f / (1.f + expf(-s)) + TEMPF;
  }
}

// Per-batch normalize-to-TN and cumsum. grid NB, block 512 (=T3).
__global__ __launch_bounds__(512) void k_cumsum(const float* __restrict__ imp, float* __restrict__ cs) {
  __shared__ float sc[T3];
  int b = blockIdx.x, tid = threadIdx.x;
  sc[tid] = imp[b * T3 + tid];
  __syncthreads();
  for (int off = 1; off < T3; off <<= 1) {  // Hillis-Steele inclusive scan
    float add = (tid >= off) ? sc[tid - off] : 0.f;
    __syncthreads();
    sc[tid] += add;
    __syncthreads();
  }
  float total = sc[T3 - 1];
  cs[b * T3 + tid] = sc[tid] * ((float)TN / total);
}

__device__ __forceinline__ float dfun(float cv, int n) {
  float d = fmaxf(cv - (float)n, 0.f);
  if (n < TN - 1) d = fminf(d, 1.f);  // last column is unclamped (pad semantics)
  return d;
}

// pooled[b][n][c] = sum_t wmat[b,t,n] * f[b,t,c]; wmat computed on the fly from cs.
__global__ __launch_bounds__(512) void k_pool(const float* __restrict__ f, const float* __restrict__ cs,
                                              float* __restrict__ pooled) {
  __shared__ float wt[T3];
  int b = blockIdx.x / TN, n = blockIdx.x % TN;
  int tid = threadIdx.x;
  {
    float c1 = cs[b * T3 + tid];
    float c0 = (tid > 0) ? cs[b * T3 + tid - 1] : 0.f;
    wt[tid] = dfun(c1, n) - dfun(c0, n);
  }
  __syncthreads();
  float acc = 0.f;
  for (int t = 0; t < T3; t++) {
    float w = wt[t];
    if (w != 0.f) acc += w * f[((size_t)b * T3 + t) * NC + tid];  // block-uniform skip
  }
  pooled[((size_t)b * TN + n) * NC + tid] = acc;
}

// Final ChannelNorm + ReLU over C, write transposed [B][C][TN].
__global__ __launch_bounds__(512) void k_final(const float* __restrict__ pooled, const float* __restrict__ gw,
                                               const float* __restrict__ gb, float* __restrict__ out) {
  __shared__ float red[16];
  int b = blockIdx.x / TN, n = blockIdx.x % TN;
  int tid = threadIdx.x;
  float v = pooled[((size_t)b * TN + n) * NC + tid];
  float s = v, q = v * v;
  blk_sum2_512(s, q, red);
  float mean = s * (1.f / NC);
  float var = fmaxf((q - s * s * (1.f / NC)) * (1.f / (NC - 1)), 0.f);
  float y = (v - mean) * rsqrtf(var + EPSF) * gw[tid] + gb[tid];
  out[((size_t)b * NC + tid) * TN + n] = fmaxf(y, 0.f);
}

extern "C" void kernel_launch(void* const* d_in, const int* in_sizes, int n_in,
                              void* d_out, int out_size, void* d_ws, size_t ws_size,
                              hipStream_t stream) {
  const float* x   = (const float*)d_in[0];
  const float* c0w = (const float*)d_in[1];  const float* c0b = (const float*)d_in[2];
  const float* c1w = (const float*)d_in[3];  const float* c1b = (const float*)d_in[4];
  const float* c2w = (const float*)d_in[5];  const float* c2b = (const float*)d_in[6];
  const float* c3w = (const float*)d_in[7];  const float* c3b = (const float*)d_in[8];
  const float* mw1 = (const float*)d_in[9];  const float* mb1 = (const float*)d_in[10];
  const float* mw2 = (const float*)d_in[11]; const float* mb2 = (const float*)d_in[12];
  const float* mw3 = (const float*)d_in[13]; const float* mb3 = (const float*)d_in[14];
  const float* n0w = (const float*)d_in[15]; const float* n0b = (const float*)d_in[16];
  const float* n1w = (const float*)d_in[17]; const float* n1b = (const float*)d_in[18];
  const float* n2w = (const float*)d_in[19]; const float* n2b = (const float*)d_in[20];
  const float* n3w = (const float*)d_in[21]; const float* n3b = (const float*)d_in[22];
  const float* n4w = (const float*)d_in[23]; const float* n4b = (const float*)d_in[24];

  float* ws = (float*)d_ws;
  // Workspace map (floats). Peak ~98.6 MB.
  float* h0 = ws;                  // [4][8192][512] = 16,777,216
  float* h1 = ws + 16777216;       // [4][2048][512] =  4,194,304
  float* h2 = h1 + 4194304;        // [4][1024][512] =  2,097,152
  float* h3 = h2 + 2097152;        // [4][ 512][512] =  1,048,576
  float* z1 = ws;                  // reuse h0 region (dead after conv1): [2048][2048]
  float* z2 = ws + 4194304;        // [2048][2048] (still inside h0 region)
  float* imp = h3 + 1048576;       // [4][512]
  float* cs  = imp + NB * T3;      // [4][512]
  float* pooled = cs + NB * T3;    // [4][256][512]
  float* outp = (float*)d_out;     // [4][512][256]

  k_conv0<<<NB * T0, 512, 0, stream>>>(x, c0w, c0b, n0w, n0b, h0);
  k_conv<T0, T1, 8, 4, 2, 4, 20><<<NB * (T1 / 4), 512, 0, stream>>>(h0, c1w, c1b, n1w, n1b, h1);
  k_conv<T1, T2, 4, 2, 1, 8, 20><<<NB * (T2 / 8), 512, 0, stream>>>(h1, c2w, c2b, n2w, n2b, h2);
  k_conv<T2, T3, 4, 2, 1, 8, 20><<<NB * (T3 / 8), 512, 0, stream>>>(h2, c3w, c3b, n3w, n3b, h3);
  k_mlp<512, true><<<NB * T3 / 8, 512, 0, stream>>>(h3, mw1, mb1, z1);
  k_mlp<2048, true><<<NB * T3 / 8, 512, 0, stream>>>(z1, mw2, mb2, z2);
  k_head<<<NB * T3, 256, 0, stream>>>(z2, mw3, mb3, imp);
  k_cumsum<<<NB, 512, 0, stream>>>(imp, cs);
  k_pool<<<NB * TN, 512, 0, stream>>>(h3, cs, pooled);
  k_final<<<NB * TN, 512, 0, stream>>>(pooled, n4w, n4b, outp);
}

// Round 2
// 517.757 us; speedup vs baseline: 5.3351x; 5.3351x over previous
//
#include <hip/hip_runtime.h>
#include <hip/hip_bf16.h>
#include <math.h>

#define NB 4
#define LIN 40960
#define NC 512
#define T0 8192
#define T1 2048
#define T2 1024
#define T3 512
#define TN 256
#define DM 2048
#define EPSF 1e-5f
#define TEMPF 1e-5f

typedef __attribute__((ext_vector_type(8))) short bf16x8;
typedef __attribute__((ext_vector_type(4))) float f32x4;

__device__ __forceinline__ int refl(int t, int T) {
  if (t < 0) t = -t;
  if (t >= T) t = 2 * T - 2 - t;
  return t;
}

// async global->LDS, 16B per lane. LDS dest is wave-uniform base + lane*16 (we pass
// per-lane ptr whose lane0 value is the wave base; HW strides by lane automatically).
__device__ __forceinline__ void gld16(void* lds, const void* g) {
  __builtin_amdgcn_global_load_lds((const __attribute__((address_space(1))) unsigned int*)g,
                                   (__attribute__((address_space(3))) unsigned int*)lds, 16, 0, 0);
}

// Block-wide sum of two values across 512 threads (8 waves).
__device__ __forceinline__ void blk_sum2_512(float& a, float& b, float* scratch) {
#pragma unroll
  for (int off = 32; off > 0; off >>= 1) {
    a += __shfl_down(a, off, 64);
    b += __shfl_down(b, off, 64);
  }
  int lane = threadIdx.x & 63, wid = threadIdx.x >> 6;
  __syncthreads();
  if (lane == 0) { scratch[wid] = a; scratch[8 + wid] = b; }
  __syncthreads();
  float sa = 0.f, sb = 0.f;
#pragma unroll
  for (int i = 0; i < 8; i++) { sa += scratch[i]; sb += scratch[8 + i]; }
  a = sa; b = sb;
}

// ---------------- weight prep ----------------
// conv w[co][ci][kk] fp32 -> Wt[co][kk*512+ci] bf16  (row-major [N=512][K=512*KT])
template <int KT>
__global__ __launch_bounds__(256) void k_prepw_conv(const float* __restrict__ w,
                                                    __hip_bfloat16* __restrict__ wt) {
  int idx = blockIdx.x * 256 + threadIdx.x;  // = co*(512*KT) + kk*512 + ci
  int co = idx / (512 * KT);
  int rem = idx - co * (512 * KT);
  int kk = rem >> 9;
  int ci = rem & 511;
  wt[idx] = __float2bfloat16(w[(size_t)co * 512 * KT + (size_t)ci * KT + kk]);
}

// mlp w[k][n] fp32 [KD][ND] -> wt[n][k] bf16, tiled transpose
template <int KD, int ND>
__global__ __launch_bounds__(256) void k_prepw_mlp(const float* __restrict__ w,
                                                   __hip_bfloat16* __restrict__ wt) {
  __shared__ float tile[32][33];
  int bx = blockIdx.x % (ND / 32);  // n-tile
  int by = blockIdx.x / (ND / 32);  // k-tile
  int tx = threadIdx.x & 31, ty = threadIdx.x >> 5;  // 32x8
#pragma unroll
  for (int i = 0; i < 32; i += 8)
    tile[ty + i][tx] = w[(size_t)(by * 32 + ty + i) * ND + bx * 32 + tx];
  __syncthreads();
#pragma unroll
  for (int i = 0; i < 32; i += 8)
    wt[(size_t)(bx * 32 + ty + i) * KD + by * 32 + tx] = __float2bfloat16(tile[tx][ty + i]);
}

// ---------------- conv0 (Cin=1) + ChannelNorm + ReLU -> bf16 ----------------
// grid NB*(T0/8), block 512. 8 timesteps per block.
__global__ __launch_bounds__(512) void k_conv0(const float* __restrict__ x, const float* __restrict__ w,
                                               const float* __restrict__ bias, const float* __restrict__ gw,
                                               const float* __restrict__ gb, __hip_bfloat16* __restrict__ out) {
  __shared__ float xv[48];
  __shared__ float red[16];
  int b = blockIdx.x / (T0 / 8);
  int t0 = (blockIdx.x % (T0 / 8)) * 8;
  int tid = threadIdx.x;
  if (tid < 45) {
    int gt = refl(t0 * 5 - 3 + tid, LIN);
    xv[tid] = x[(size_t)b * LIN + gt];
  }
  __syncthreads();
  float wk[10];
#pragma unroll
  for (int k = 0; k < 10; k++) wk[k] = w[tid * 10 + k];
  float acc[8];
#pragma unroll
  for (int tt = 0; tt < 8; tt++) {
    float a = bias[tid];
#pragma unroll
    for (int k = 0; k < 10; k++) a += xv[tt * 5 + k] * wk[k];
    acc[tt] = a;
  }
#pragma unroll
  for (int tt = 0; tt < 8; tt++) {
    float s = acc[tt], q = acc[tt] * acc[tt];
    blk_sum2_512(s, q, red);
    float mean = s * (1.f / NC);
    float var = fmaxf((q - s * s * (1.f / NC)) * (1.f / (NC - 1)), 0.f);
    float y = (acc[tt] - mean) * rsqrtf(var + EPSF) * gw[tid] + gb[tid];
    out[((size_t)(b * T0 + t0 + tt)) * NC + tid] = __float2bfloat16(fmaxf(y, 0.f));
  }
}

// ---------------- MFMA GEMM ----------------
// C[M][NN] = A[M][K] @ Wt[NN][K]^T. A bf16 (MODE1: implicit im2col w/ reflect pad).
// 128x128 tile, BK=32, 256 threads = 4 waves in 2x2, each wave 64x64 via 4x4 16x16x32 mfma.
// EPI 0: store raw fp32 to Cf. EPI 1: bias+exact GELU -> bf16 Cb.
template <int MODE, int TIN_, int TOUT_, int SS, int PP, int KK, int NN, int EPI>
__global__ __launch_bounds__(256) void k_gemm(const __hip_bfloat16* __restrict__ A,
                                              const __hip_bfloat16* __restrict__ Bt,
                                              const float* __restrict__ bias,
                                              float* __restrict__ Cf,
                                              __hip_bfloat16* __restrict__ Cb) {
  __shared__ __align__(16) __hip_bfloat16 sA[128 * 32];
  __shared__ __align__(16) __hip_bfloat16 sB[128 * 32];
  const int tid = threadIdx.x;
  const int lane = tid & 63;
  const int wave = tid >> 6;
  const int wm = wave >> 1, wn = wave & 1;
  const int nt = NN / 128;
  const int row0 = (blockIdx.x / nt) * 128;
  const int col0 = (blockIdx.x % nt) * 128;
  const int cq = lane >> 4, cl = lane & 15;

  f32x4 acc[4][4];
  const f32x4 zz = {0.f, 0.f, 0.f, 0.f};
#pragma unroll
  for (int mi = 0; mi < 4; mi++)
#pragma unroll
    for (int ni = 0; ni < 4; ni++) acc[mi][ni] = zz;

  for (int kb = 0; kb < KK / 32; kb++) {
    // stage A tile [128 m][32 k] bf16 = 8KB: 512 16B-chunks, 2 rounds x 256 threads
#pragma unroll
    for (int rr = 0; rr < 2; rr++) {
      int c = rr * 256 + tid;
      int m = c >> 2, kc = c & 3;
      size_t ga;
      if (MODE == 0) {
        ga = (size_t)(row0 + m) * KK + kb * 32 + kc * 8;
      } else {
        int r = row0 + m;
        int bb = r / TOUT_;
        int t = r - bb * TOUT_;
        int k = (kb * 32) >> 9;   // tap index (512 ci per tap)
        int ci = (kb * 32) & 511;
        int gt = refl(t * SS - PP + k, TIN_);
        ga = (((size_t)(bb * TIN_ + gt)) << 9) + ci + kc * 8;
      }
      gld16((char*)sA + c * 16, (const char*)(A + ga));
    }
    // stage Bt tile [128 n][32 k]
#pragma unroll
    for (int rr = 0; rr < 2; rr++) {
      int c = rr * 256 + tid;
      int n = c >> 2, kc = c & 3;
      size_t gbk = (size_t)(col0 + n) * KK + kb * 32 + kc * 8;
      gld16((char*)sB + c * 16, (const char*)(Bt + gbk));
    }
    __syncthreads();  // drains vmcnt before LDS reads

    bf16x8 af[4], bfr[4];
#pragma unroll
    for (int mi = 0; mi < 4; mi++)
      af[mi] = *(const bf16x8*)((const short*)sA + (wm * 64 + mi * 16 + cl) * 32 + cq * 8);
#pragma unroll
    for (int ni = 0; ni < 4; ni++)
      bfr[ni] = *(const bf16x8*)((const short*)sB + (wn * 64 + ni * 16 + cl) * 32 + cq * 8);
#pragma unroll
    for (int mi = 0; mi < 4; mi++)
#pragma unroll
      for (int ni = 0; ni < 4; ni++)
        acc[mi][ni] = __builtin_amdgcn_mfma_f32_16x16x32_bf16(af[mi], bfr[ni], acc[mi][ni], 0, 0, 0);
    __syncthreads();
  }

  // epilogue. C/D layout: col=lane&15, row=(lane>>4)*4+reg  [m89/m91]
#pragma unroll
  for (int mi = 0; mi < 4; mi++)
#pragma unroll
    for (int ni = 0; ni < 4; ni++)
#pragma unroll
      for (int r2 = 0; r2 < 4; r2++) {
        int row = row0 + wm * 64 + mi * 16 + cq * 4 + r2;
        int col = col0 + wn * 64 + ni * 16 + cl;
        float v = acc[mi][ni][r2];
        if (EPI == 1) {
          v += bias[col];
          v = 0.5f * v * (1.f + erff(v * 0.70710678118654752f));
          Cb[(size_t)row * NN + col] = __float2bfloat16(v);
        } else {
          Cf[(size_t)row * NN + col] = v;
        }
      }
}

// ---------------- ChannelNorm (+conv bias) + ReLU -> bf16. grid=M rows ----------------
__global__ __launch_bounds__(512) void k_cnorm(const float* __restrict__ g, const float* __restrict__ cb,
                                               const float* __restrict__ gw, const float* __restrict__ gb,
                                               __hip_bfloat16* __restrict__ out) {
  __shared__ float red[16];
  size_t row = blockIdx.x;
  int tid = threadIdx.x;
  float v = g[row * NC + tid] + cb[tid];
  float s = v, q = v * v;
  blk_sum2_512(s, q, red);
  float mean = s * (1.f / NC);
  float var = fmaxf((q - s * s * (1.f / NC)) * (1.f / (NC - 1)), 0.f);
  float y = (v - mean) * rsqrtf(var + EPSF) * gw[tid] + gb[tid];
  out[row * NC + tid] = __float2bfloat16(fmaxf(y, 0.f));
}

// ---------------- head: sigmoid(z @ w3 + b3) + TEMP ----------------
__global__ __launch_bounds__(256) void k_head(const __hip_bfloat16* __restrict__ z, const float* __restrict__ w,
                                              const float* __restrict__ bias, float* __restrict__ imp) {
  __shared__ float red[4];
  int row = blockIdx.x, tid = threadIdx.x;
  float a = 0.f;
  for (int i = tid; i < DM; i += 256) a += __bfloat162float(z[(size_t)row * DM + i]) * w[i];
#pragma unroll
  for (int off = 32; off > 0; off >>= 1) a += __shfl_down(a, off, 64);
  int lane = tid & 63, wid = tid >> 6;
  if (lane == 0) red[wid] = a;
  __syncthreads();
  if (tid == 0) {
    float s = red[0] + red[1] + red[2] + red[3] + bias[0];
    imp[row] = 1.f / (1.f + expf(-s)) + TEMPF;
  }
}

__global__ __launch_bounds__(512) void k_cumsum(const float* __restrict__ imp, float* __restrict__ cs) {
  __shared__ float sc[T3];
  int b = blockIdx.x, tid = threadIdx.x;
  sc[tid] = imp[b * T3 + tid];
  __syncthreads();
  for (int off = 1; off < T3; off <<= 1) {
    float add = (tid >= off) ? sc[tid - off] : 0.f;
    __syncthreads();
    sc[tid] += add;
    __syncthreads();
  }
  float total = sc[T3 - 1];
  cs[b * T3 + tid] = sc[tid] * ((float)TN / total);
}

__device__ __forceinline__ float dfun(float cv, int n) {
  float d = fmaxf(cv - (float)n, 0.f);
  if (n < TN - 1) d = fminf(d, 1.f);
  return d;
}

__global__ __launch_bounds__(512) void k_pool(const __hip_bfloat16* __restrict__ f, const float* __restrict__ cs,
                                              float* __restrict__ pooled) {
  __shared__ float wt[T3];
  int b = blockIdx.x / TN, n = blockIdx.x % TN;
  int tid = threadIdx.x;
  {
    float c1 = cs[b * T3 + tid];
    float c0 = (tid > 0) ? cs[b * T3 + tid - 1] : 0.f;
    wt[tid] = dfun(c1, n) - dfun(c0, n);
  }
  __syncthreads();
  float acc = 0.f;
  for (int t = 0; t < T3; t++) {
    float w = wt[t];
    if (w != 0.f) acc += w * __bfloat162float(f[((size_t)b * T3 + t) * NC + tid]);
  }
  pooled[((size_t)b * TN + n) * NC + tid] = acc;
}

__global__ __launch_bounds__(512) void k_final(const float* __restrict__ pooled, const float* __restrict__ gw,
                                               const float* __restrict__ gb, float* __restrict__ out) {
  __shared__ float red[16];
  int b = blockIdx.x / TN, n = blockIdx.x % TN;
  int tid = threadIdx.x;
  float v = pooled[((size_t)b * TN + n) * NC + tid];
  float s = v, q = v * v;
  blk_sum2_512(s, q, red);
  float mean = s * (1.f / NC);
  float var = fmaxf((q - s * s * (1.f / NC)) * (1.f / (NC - 1)), 0.f);
  float y = (v - mean) * rsqrtf(var + EPSF) * gw[tid] + gb[tid];
  out[((size_t)b * NC + tid) * TN + n] = fmaxf(y, 0.f);
}

extern "C" void kernel_launch(void* const* d_in, const int* in_sizes, int n_in,
                              void* d_out, int out_size, void* d_ws, size_t ws_size,
                              hipStream_t stream) {
  const float* x   = (const float*)d_in[0];
  const float* c0w = (const float*)d_in[1];  const float* c0b = (const float*)d_in[2];
  const float* c1w = (const float*)d_in[3];  const float* c1b = (const float*)d_in[4];
  const float* c2w = (const float*)d_in[5];  const float* c2b = (const float*)d_in[6];
  const float* c3w = (const float*)d_in[7];  const float* c3b = (const float*)d_in[8];
  const float* mw1 = (const float*)d_in[9];  const float* mb1 = (const float*)d_in[10];
  const float* mw2 = (const float*)d_in[11]; const float* mb2 = (const float*)d_in[12];
  const float* mw3 = (const float*)d_in[13]; const float* mb3 = (const float*)d_in[14];
  const float* n0w = (const float*)d_in[15]; const float* n0b = (const float*)d_in[16];
  const float* n1w = (const float*)d_in[17]; const float* n1b = (const float*)d_in[18];
  const float* n2w = (const float*)d_in[19]; const float* n2b = (const float*)d_in[20];
  const float* n3w = (const float*)d_in[21]; const float* n3b = (const float*)d_in[22];
  const float* n4w = (const float*)d_in[23]; const float* n4b = (const float*)d_in[24];

  char* base = (char*)d_ws;
  // Workspace map (bytes). Total 83 MB.
  __hip_bfloat16* h0b  = (__hip_bfloat16*)(base);                     // 32 MB [dead after conv1 gemm]
  float*          g    = (float*)(base + (32u << 20));                // 16 MB fp32 gemm scratch
  __hip_bfloat16* h1b  = (__hip_bfloat16*)(base + (48u << 20));       // 8 MB
  __hip_bfloat16* h2b  = (__hip_bfloat16*)(base + (56u << 20));       // 4 MB
  __hip_bfloat16* h3b  = (__hip_bfloat16*)(base + (60u << 20));       // 2 MB
  float*          pooled = (float*)(base + (62u << 20));              // 2 MB
  float*          imp  = (float*)(base + (64u << 20));                // 8 KB
  float*          cs   = (float*)(base + (64u << 20) + 8192);         // 8 KB
  __hip_bfloat16* wt1  = (__hip_bfloat16*)(base + (65u << 20));       // 4 MB
  __hip_bfloat16* wt2  = (__hip_bfloat16*)(base + (69u << 20));       // 2 MB
  __hip_bfloat16* wt3  = (__hip_bfloat16*)(base + (71u << 20));       // 2 MB
  __hip_bfloat16* wm1t = (__hip_bfloat16*)(base + (73u << 20));       // 2 MB
  __hip_bfloat16* wm2t = (__hip_bfloat16*)(base + (75u << 20));       // 8 MB (ends 83 MB)
  __hip_bfloat16* z1b  = h0b;                                         // reuse (8 MB)
  __hip_bfloat16* z2b  = (__hip_bfloat16*)(base + (8u << 20));        // reuse (8 MB)
  float* outp = (float*)d_out;

  // weight prep
  k_prepw_conv<8><<<512 * 512 * 8 / 256, 256, 0, stream>>>(c1w, wt1);
  k_prepw_conv<4><<<512 * 512 * 4 / 256, 256, 0, stream>>>(c2w, wt2);
  k_prepw_conv<4><<<512 * 512 * 4 / 256, 256, 0, stream>>>(c3w, wt3);
  k_prepw_mlp<512, 2048><<<(2048 / 32) * (512 / 32), 256, 0, stream>>>(mw1, wm1t);
  k_prepw_mlp<2048, 2048><<<(2048 / 32) * (2048 / 32), 256, 0, stream>>>(mw2, wm2t);

  // conv0 + norm -> bf16
  k_conv0<<<NB * (T0 / 8), 512, 0, stream>>>(x, c0w, c0b, n0w, n0b, h0b);

  // conv1: M=8192, K=4096, N=512
  k_gemm<1, 8192, 2048, 4, 2, 4096, 512, 0><<<64 * 4, 256, 0, stream>>>(h0b, wt1, nullptr, g, nullptr);
  k_cnorm<<<NB * T1, 512, 0, stream>>>(g, c1b, n1w, n1b, h1b);
  // conv2: M=4096, K=2048, N=512
  k_gemm<1, 2048, 1024, 2, 1, 2048, 512, 0><<<32 * 4, 256, 0, stream>>>(h1b, wt2, nullptr, g, nullptr);
  k_cnorm<<<NB * T2, 512, 0, stream>>>(g, c2b, n2w, n2b, h2b);
  // conv3: M=2048, K=2048, N=512
  k_gemm<1, 1024, 512, 2, 1, 2048, 512, 0><<<16 * 4, 256, 0, stream>>>(h2b, wt3, nullptr, g, nullptr);
  k_cnorm<<<NB * T3, 512, 0, stream>>>(g, c3b, n3w, n3b, h3b);

  // mlp1: M=2048, K=512, N=2048 (bias+GELU -> bf16)
  k_gemm<0, 0, 1, 0, 0, 512, 2048, 1><<<16 * 16, 256, 0, stream>>>(h3b, wm1t, mb1, nullptr, z1b);
  // mlp2: M=2048, K=2048, N=2048
  k_gemm<0, 0, 1, 0, 0, 2048, 2048, 1><<<16 * 16, 256, 0, stream>>>(z1b, wm2t, mb2, nullptr, z2b);

  k_head<<<NB * T3, 256, 0, stream>>>(z2b, mw3, mb3, imp);
  k_cumsum<<<NB, 512, 0, stream>>>(imp, cs);
  k_pool<<<NB * TN, 512, 0, stream>>>(h3b, cs, pooled);
  k_final<<<NB * TN, 512, 0, stream>>>(pooled, n4w, n4b, outp);
}

// Round 3
// 394.514 us; speedup vs baseline: 7.0017x; 1.3124x over previous
//
#include <hip/hip_runtime.h>
#include <hip/hip_bf16.h>
#include <math.h>

#define NB 4
#define LIN 40960
#define NC 512
#define T0 8192
#define T1 2048
#define T2 1024
#define T3 512
#define TN 256
#define DM 2048
#define EPSF 1e-5f
#define TEMPF 1e-5f

typedef __attribute__((ext_vector_type(8))) short bf16x8;
typedef __attribute__((ext_vector_type(4))) float f32x4;

__device__ __forceinline__ int refl(int t, int T) {
  if (t < 0) t = -t;
  if (t >= T) t = 2 * T - 2 - t;
  return t;
}

__device__ __forceinline__ void gld16(void* lds, const void* g) {
  __builtin_amdgcn_global_load_lds((const __attribute__((address_space(1))) unsigned int*)g,
                                   (__attribute__((address_space(3))) unsigned int*)lds, 16, 0, 0);
}

// Block-wide sum of two values across 512 threads (used by k_final only).
__device__ __forceinline__ void blk_sum2_512(float& a, float& b, float* scratch) {
#pragma unroll
  for (int off = 32; off > 0; off >>= 1) {
    a += __shfl_down(a, off, 64);
    b += __shfl_down(b, off, 64);
  }
  int lane = threadIdx.x & 63, wid = threadIdx.x >> 6;
  __syncthreads();
  if (lane == 0) { scratch[wid] = a; scratch[8 + wid] = b; }
  __syncthreads();
  float sa = 0.f, sb = 0.f;
#pragma unroll
  for (int i = 0; i < 8; i++) { sa += scratch[i]; sb += scratch[8 + i]; }
  a = sa; b = sb;
}

// ---------------- weight prep ----------------
// conv w[co][ci][kk] -> wt[co][kk*512+ci] bf16, via LDS (coalesced both sides)
template <int KT>
__global__ __launch_bounds__(256) void k_prepw_conv(const float* __restrict__ w,
                                                    __hip_bfloat16* __restrict__ wt) {
  __shared__ float l[512 * KT];
  int co = blockIdx.x;
  const float* wb = w + (size_t)co * 512 * KT;
  for (int i = threadIdx.x; i < 512 * KT; i += 256) l[i] = wb[i];
  __syncthreads();
  __hip_bfloat16* wo = wt + (size_t)co * 512 * KT;
  for (int i = threadIdx.x; i < 512 * KT; i += 256) {
    int kk = i >> 9, ci = i & 511;
    wo[i] = __float2bfloat16(l[ci * KT + kk]);
  }
}

// mlp w[k][n] fp32 [KD][ND] -> wt[n][k] bf16, tiled transpose
template <int KD, int ND>
__global__ __launch_bounds__(256) void k_prepw_mlp(const float* __restrict__ w,
                                                   __hip_bfloat16* __restrict__ wt) {
  __shared__ float tile[32][33];
  int bx = blockIdx.x % (ND / 32);
  int by = blockIdx.x / (ND / 32);
  int tx = threadIdx.x & 31, ty = threadIdx.x >> 5;
#pragma unroll
  for (int i = 0; i < 32; i += 8)
    tile[ty + i][tx] = w[(size_t)(by * 32 + ty + i) * ND + bx * 32 + tx];
  __syncthreads();
#pragma unroll
  for (int i = 0; i < 32; i += 8)
    wt[(size_t)(bx * 32 + ty + i) * KD + by * 32 + tx] = __float2bfloat16(tile[tx][ty + i]);
}

// ---------------- conv0 + ChannelNorm + ReLU -> bf16 ----------------
// Block = (b, 8 timesteps), tid = channel. Batched transpose-reduce: 3 barriers total.
__global__ __launch_bounds__(512) void k_conv0(const float* __restrict__ x, const float* __restrict__ w,
                                               const float* __restrict__ bias, const float* __restrict__ gw,
                                               const float* __restrict__ gb, __hip_bfloat16* __restrict__ out) {
  __shared__ float xv[48];
  __shared__ float tb[512 * 9];  // acc transposed [c][tt], pad 9
  __shared__ float stats[16];    // mean[8], rstd[8]
  int b = blockIdx.x / (T0 / 8);
  int t0 = (blockIdx.x % (T0 / 8)) * 8;
  int tid = threadIdx.x;
  if (tid < 45) xv[tid] = x[(size_t)b * LIN + refl(t0 * 5 - 3 + tid, LIN)];
  __syncthreads();
  float wk[10];
#pragma unroll
  for (int k = 0; k < 10; k++) wk[k] = w[tid * 10 + k];
  float bs = bias[tid];
  float acc[8];
#pragma unroll
  for (int tt = 0; tt < 8; tt++) {
    float a = bs;
#pragma unroll
    for (int k = 0; k < 10; k++) a += xv[tt * 5 + k] * wk[k];
    acc[tt] = a;
    tb[tid * 9 + tt] = a;
  }
  __syncthreads();
  int wave = tid >> 6, lane = tid & 63;
  float s = 0.f, q = 0.f;
#pragma unroll
  for (int j = 0; j < 8; j++) {
    float v = tb[(lane * 8 + j) * 9 + wave];
    s += v; q += v * v;
  }
#pragma unroll
  for (int off = 32; off > 0; off >>= 1) {
    s += __shfl_xor(s, off, 64);
    q += __shfl_xor(q, off, 64);
  }
  if (lane == 0) {
    float mean = s * (1.f / NC);
    float var = fmaxf((q - s * s * (1.f / NC)) * (1.f / (NC - 1)), 0.f);
    stats[wave] = mean;
    stats[8 + wave] = rsqrtf(var + EPSF);
  }
  __syncthreads();
  float gwv = gw[tid], gbv = gb[tid];
#pragma unroll
  for (int tt = 0; tt < 8; tt++) {
    float y = (acc[tt] - stats[tt]) * stats[8 + tt] * gwv + gbv;
    out[((size_t)(b * T0 + t0 + tt)) * NC + tid] = __float2bfloat16(fmaxf(y, 0.f));
  }
}

// ---------------- MFMA GEMM: 64x128 tile, BK=32, 256 thr (4 waves 2x2, wave=32x64) ----
// XCD swizzle: all nt col-tiles of a row-tile land on one XCD (assumes round-robin %8).
// EPI 0: +bias, store fp32. EPI 1: +bias, exact GELU -> bf16.
template <int MODE, int TIN_, int TOUT_, int SS, int PP, int KK, int NN, int EPI>
__global__ __launch_bounds__(256) void k_gemm(const __hip_bfloat16* __restrict__ A,
                                              const __hip_bfloat16* __restrict__ Bt,
                                              const float* __restrict__ bias,
                                              float* __restrict__ Cf,
                                              __hip_bfloat16* __restrict__ Cb) {
  __shared__ __align__(16) __hip_bfloat16 sA[64 * 32];
  __shared__ __align__(16) __hip_bfloat16 sB[128 * 32];
  const int tid = threadIdx.x;
  const int lane = tid & 63;
  const int wave = tid >> 6;
  const int wm = wave >> 1, wn = wave & 1;
  constexpr int nt = NN / 128;
  // swizzle: xcd = blk&7, slot = blk>>3; row-tile r == xcd (mod 8)
  const int blk = blockIdx.x;
  const int xs = blk & 7, sl = blk >> 3;
  const int row0 = ((sl / nt) * 8 + xs) * 64;
  const int col0 = (sl % nt) * 128;
  const int cq = lane >> 4, cl = lane & 15;

  f32x4 acc[2][4];
  const f32x4 zz = {0.f, 0.f, 0.f, 0.f};
#pragma unroll
  for (int mi = 0; mi < 2; mi++)
#pragma unroll
    for (int ni = 0; ni < 4; ni++) acc[mi][ni] = zz;

  for (int kb = 0; kb < KK / 32; kb++) {
    // stage A [64 m][32 k] = 4KB: 256 chunks of 16B, 1 round
    {
      int m = tid >> 2, kc = tid & 3;
      size_t ga;
      if (MODE == 0) {
        ga = (size_t)(row0 + m) * KK + kb * 32 + kc * 8;
      } else {
        int r = row0 + m;
        int bb = r / TOUT_;
        int t = r - bb * TOUT_;
        int k = (kb * 32) >> 9;
        int ci = ((kb * 32) & 511) + kc * 8;
        int gt = refl(t * SS - PP + k, TIN_);
        ga = (((size_t)(bb * TIN_ + gt)) << 9) + ci;
      }
      gld16((char*)sA + tid * 16, (const char*)(A + ga));
    }
    // stage Bt [128 n][32 k] = 8KB: 2 rounds
#pragma unroll
    for (int rr = 0; rr < 2; rr++) {
      int c = rr * 256 + tid;
      int n = c >> 2, kc = c & 3;
      size_t gbk = (size_t)(col0 + n) * KK + kb * 32 + kc * 8;
      gld16((char*)sB + c * 16, (const char*)(Bt + gbk));
    }
    __syncthreads();

    bf16x8 af[2], bfr[4];
#pragma unroll
    for (int mi = 0; mi < 2; mi++)
      af[mi] = *(const bf16x8*)((const short*)sA + (wm * 32 + mi * 16 + cl) * 32 + cq * 8);
#pragma unroll
    for (int ni = 0; ni < 4; ni++)
      bfr[ni] = *(const bf16x8*)((const short*)sB + (wn * 64 + ni * 16 + cl) * 32 + cq * 8);
#pragma unroll
    for (int mi = 0; mi < 2; mi++)
#pragma unroll
      for (int ni = 0; ni < 4; ni++)
        acc[mi][ni] = __builtin_amdgcn_mfma_f32_16x16x32_bf16(af[mi], bfr[ni], acc[mi][ni], 0, 0, 0);
    __syncthreads();
  }

  // epilogue; C/D: col=lane&15, row=(lane>>4)*4+reg
#pragma unroll
  for (int mi = 0; mi < 2; mi++)
#pragma unroll
    for (int ni = 0; ni < 4; ni++)
#pragma unroll
      for (int r2 = 0; r2 < 4; r2++) {
        int row = row0 + wm * 32 + mi * 16 + cq * 4 + r2;
        int col = col0 + wn * 64 + ni * 16 + cl;
        float v = acc[mi][ni][r2] + bias[col];
        if (EPI == 1) {
          v = 0.5f * v * (1.f + erff(v * 0.70710678118654752f));
          Cb[(size_t)row * NN + col] = __float2bfloat16(v);
        } else {
          Cf[(size_t)row * NN + col] = v;
        }
      }
}

// ---------------- ChannelNorm + ReLU -> bf16. One wave per row, no barriers ----------
__global__ __launch_bounds__(512) void k_cnorm(const float* __restrict__ g,
                                               const float* __restrict__ gw, const float* __restrict__ gb,
                                               __hip_bfloat16* __restrict__ out) {
  int wave = threadIdx.x >> 6, lane = threadIdx.x & 63;
  size_t row = (size_t)blockIdx.x * 8 + wave;
  const float* gr = g + row * NC + lane * 8;
  float4 a0 = *(const float4*)gr;
  float4 a1 = *(const float4*)(gr + 4);
  float v[8] = {a0.x, a0.y, a0.z, a0.w, a1.x, a1.y, a1.z, a1.w};
  float s = 0.f, q = 0.f;
#pragma unroll
  for (int j = 0; j < 8; j++) { s += v[j]; q += v[j] * v[j]; }
#pragma unroll
  for (int off = 32; off > 0; off >>= 1) {
    s += __shfl_xor(s, off, 64);
    q += __shfl_xor(q, off, 64);
  }
  float mean = s * (1.f / NC);
  float var = fmaxf((q - s * s * (1.f / NC)) * (1.f / (NC - 1)), 0.f);
  float rstd = rsqrtf(var + EPSF);
  float4 w0 = *(const float4*)(gw + lane * 8), w1 = *(const float4*)(gw + lane * 8 + 4);
  float4 b0 = *(const float4*)(gb + lane * 8), b1 = *(const float4*)(gb + lane * 8 + 4);
  float gwv[8] = {w0.x, w0.y, w0.z, w0.w, w1.x, w1.y, w1.z, w1.w};
  float gbv[8] = {b0.x, b0.y, b0.z, b0.w, b1.x, b1.y, b1.z, b1.w};
  union { __hip_bfloat16 h[8]; uint4 u; } pk;
#pragma unroll
  for (int j = 0; j < 8; j++)
    pk.h[j] = __float2bfloat16(fmaxf((v[j] - mean) * rstd * gwv[j] + gbv[j], 0.f));
  *(uint4*)(out + row * NC + lane * 8) = pk.u;
}

// ---------------- head: sigmoid(z @ w3 + b3) + TEMP ----------------
__global__ __launch_bounds__(256) void k_head(const __hip_bfloat16* __restrict__ z, const float* __restrict__ w,
                                              const float* __restrict__ bias, float* __restrict__ imp) {
  __shared__ float red[4];
  int row = blockIdx.x, tid = threadIdx.x;
  float a = 0.f;
  for (int i = tid; i < DM; i += 256) a += __bfloat162float(z[(size_t)row * DM + i]) * w[i];
#pragma unroll
  for (int off = 32; off > 0; off >>= 1) a += __shfl_down(a, off, 64);
  int lane = tid & 63, wid = tid >> 6;
  if (lane == 0) red[wid] = a;
  __syncthreads();
  if (tid == 0) {
    float s = red[0] + red[1] + red[2] + red[3] + bias[0];
    imp[row] = 1.f / (1.f + expf(-s)) + TEMPF;
  }
}

__global__ __launch_bounds__(512) void k_cumsum(const float* __restrict__ imp, float* __restrict__ cs) {
  __shared__ float sc[T3];
  int b = blockIdx.x, tid = threadIdx.x;
  sc[tid] = imp[b * T3 + tid];
  __syncthreads();
  for (int off = 1; off < T3; off <<= 1) {
    float add = (tid >= off) ? sc[tid - off] : 0.f;
    __syncthreads();
    sc[tid] += add;
    __syncthreads();
  }
  float total = sc[T3 - 1];
  cs[b * T3 + tid] = sc[tid] * ((float)TN / total);
}

__device__ __forceinline__ float dfun(float cv, int n) {
  float d = fmaxf(cv - (float)n, 0.f);
  if (n < TN - 1) d = fminf(d, 1.f);
  return d;
}

__global__ __launch_bounds__(512) void k_pool(const __hip_bfloat16* __restrict__ f, const float* __restrict__ cs,
                                              float* __restrict__ pooled) {
  __shared__ float wt[T3];
  int b = blockIdx.x / TN, n = blockIdx.x % TN;
  int tid = threadIdx.x;
  {
    float c1 = cs[b * T3 + tid];
    float c0 = (tid > 0) ? cs[b * T3 + tid - 1] : 0.f;
    wt[tid] = dfun(c1, n) - dfun(c0, n);
  }
  __syncthreads();
  float acc = 0.f;
  for (int t = 0; t < T3; t++) {
    float w = wt[t];
    if (w != 0.f) acc += w * __bfloat162float(f[((size_t)b * T3 + t) * NC + tid]);
  }
  pooled[((size_t)b * TN + n) * NC + tid] = acc;
}

__global__ __launch_bounds__(512) void k_final(const float* __restrict__ pooled, const float* __restrict__ gw,
                                               const float* __restrict__ gb, float* __restrict__ out) {
  __shared__ float red[16];
  int b = blockIdx.x / TN, n = blockIdx.x % TN;
  int tid = threadIdx.x;
  float v = pooled[((size_t)b * TN + n) * NC + tid];
  float s = v, q = v * v;
  blk_sum2_512(s, q, red);
  float mean = s * (1.f / NC);
  float var = fmaxf((q - s * s * (1.f / NC)) * (1.f / (NC - 1)), 0.f);
  float y = (v - mean) * rsqrtf(var + EPSF) * gw[tid] + gb[tid];
  out[((size_t)b * NC + tid) * TN + n] = fmaxf(y, 0.f);
}

extern "C" void kernel_launch(void* const* d_in, const int* in_sizes, int n_in,
                              void* d_out, int out_size, void* d_ws, size_t ws_size,
                              hipStream_t stream) {
  const float* x   = (const float*)d_in[0];
  const float* c0w = (const float*)d_in[1];  const float* c0b = (const float*)d_in[2];
  const float* c1w = (const float*)d_in[3];  const float* c1b = (const float*)d_in[4];
  const float* c2w = (const float*)d_in[5];  const float* c2b = (const float*)d_in[6];
  const float* c3w = (const float*)d_in[7];  const float* c3b = (const float*)d_in[8];
  const float* mw1 = (const float*)d_in[9];  const float* mb1 = (const float*)d_in[10];
  const float* mw2 = (const float*)d_in[11]; const float* mb2 = (const float*)d_in[12];
  const float* mw3 = (const float*)d_in[13]; const float* mb3 = (const float*)d_in[14];
  const float* n0w = (const float*)d_in[15]; const float* n0b = (const float*)d_in[16];
  const float* n1w = (const float*)d_in[17]; const float* n1b = (const float*)d_in[18];
  const float* n2w = (const float*)d_in[19]; const float* n2b = (const float*)d_in[20];
  const float* n3w = (const float*)d_in[21]; const float* n3b = (const float*)d_in[22];
  const float* n4w = (const float*)d_in[23]; const float* n4b = (const float*)d_in[24];

  char* base = (char*)d_ws;
  __hip_bfloat16* h0b  = (__hip_bfloat16*)(base);                     // 32 MB [dead after conv1 gemm]
  float*          g    = (float*)(base + (32u << 20));                // 16 MB fp32 gemm scratch
  __hip_bfloat16* h1b  = (__hip_bfloat16*)(base + (48u << 20));       // 8 MB
  __hip_bfloat16* h2b  = (__hip_bfloat16*)(base + (56u << 20));       // 4 MB
  __hip_bfloat16* h3b  = (__hip_bfloat16*)(base + (60u << 20));       // 2 MB
  float*          pooled = (float*)(base + (62u << 20));              // 2 MB
  float*          imp  = (float*)(base + (64u << 20));                // 8 KB
  float*          cs   = (float*)(base + (64u << 20) + 8192);         // 8 KB
  __hip_bfloat16* wt1  = (__hip_bfloat16*)(base + (65u << 20));       // 4 MB
  __hip_bfloat16* wt2  = (__hip_bfloat16*)(base + (69u << 20));       // 2 MB
  __hip_bfloat16* wt3  = (__hip_bfloat16*)(base + (71u << 20));       // 2 MB
  __hip_bfloat16* wm1t = (__hip_bfloat16*)(base + (73u << 20));       // 2 MB
  __hip_bfloat16* wm2t = (__hip_bfloat16*)(base + (75u << 20));       // 8 MB
  __hip_bfloat16* z1b  = h0b;
  __hip_bfloat16* z2b  = (__hip_bfloat16*)(base + (8u << 20));
  float* outp = (float*)d_out;

  // weight prep
  k_prepw_conv<8><<<512, 256, 0, stream>>>(c1w, wt1);
  k_prepw_conv<4><<<512, 256, 0, stream>>>(c2w, wt2);
  k_prepw_conv<4><<<512, 256, 0, stream>>>(c3w, wt3);
  k_prepw_mlp<512, 2048><<<(2048 / 32) * (512 / 32), 256, 0, stream>>>(mw1, wm1t);
  k_prepw_mlp<2048, 2048><<<(2048 / 32) * (2048 / 32), 256, 0, stream>>>(mw2, wm2t);

  k_conv0<<<NB * (T0 / 8), 512, 0, stream>>>(x, c0w, c0b, n0w, n0b, h0b);

  // conv1: M=8192 (mt=128), K=4096, N=512 (nt=4) -> 512 blocks
  k_gemm<1, 8192, 2048, 4, 2, 4096, 512, 0><<<128 * 4, 256, 0, stream>>>(h0b, wt1, c1b, g, nullptr);
  k_cnorm<<<8192 / 8, 512, 0, stream>>>(g, n1w, n1b, h1b);
  // conv2: M=4096 (mt=64), K=2048 -> 256 blocks
  k_gemm<1, 2048, 1024, 2, 1, 2048, 512, 0><<<64 * 4, 256, 0, stream>>>(h1b, wt2, c2b, g, nullptr);
  k_cnorm<<<4096 / 8, 512, 0, stream>>>(g, n2w, n2b, h2b);
  // conv3: M=2048 (mt=32), K=2048 -> 128 blocks
  k_gemm<1, 1024, 512, 2, 1, 2048, 512, 0><<<32 * 4, 256, 0, stream>>>(h2b, wt3, c3b, g, nullptr);
  k_cnorm<<<2048 / 8, 512, 0, stream>>>(g, n3w, n3b, h3b);

  // mlp1: M=2048 (mt=32), K=512, N=2048 (nt=16) -> 512 blocks
  k_gemm<0, 0, 1, 0, 0, 512, 2048, 1><<<32 * 16, 256, 0, stream>>>(h3b, wm1t, mb1, nullptr, z1b);
  // mlp2: M=2048, K=2048, N=2048 -> 512 blocks
  k_gemm<0, 0, 1, 0, 0, 2048, 2048, 1><<<32 * 16, 256, 0, stream>>>(z1b, wm2t, mb2, nullptr, z2b);

  k_head<<<NB * T3, 256, 0, stream>>>(z2b, mw3, mb3, imp);
  k_cumsum<<<NB, 512, 0, stream>>>(imp, cs);
  k_pool<<<NB * TN, 512, 0, stream>>>(h3b, cs, pooled);
  k_final<<<NB * TN, 512, 0, stream>>>(pooled, n4w, n4b, outp);
}

// Round 4
// 381.281 us; speedup vs baseline: 7.2447x; 1.0347x over previous
//
#include <hip/hip_runtime.h>
#include <hip/hip_bf16.h>
#include <math.h>

#define NB 4
#define LIN 40960
#define NC 512
#define T0 8192
#define T1 2048
#define T2 1024
#define T3 512
#define TN 256
#define DM 2048
#define EPSF 1e-5f
#define TEMPF 1e-5f

typedef __attribute__((ext_vector_type(8))) short bf16x8;
typedef __attribute__((ext_vector_type(4))) float f32x4;

__device__ __forceinline__ int refl(int t, int T) {
  if (t < 0) t = -t;
  if (t >= T) t = 2 * T - 2 - t;
  return t;
}

__device__ __forceinline__ void gld16(void* lds, const void* g) {
  __builtin_amdgcn_global_load_lds((const __attribute__((address_space(1))) unsigned int*)g,
                                   (__attribute__((address_space(3))) unsigned int*)lds, 16, 0, 0);
}

__device__ __forceinline__ void blk_sum2_512(float& a, float& b, float* scratch) {
#pragma unroll
  for (int off = 32; off > 0; off >>= 1) {
    a += __shfl_down(a, off, 64);
    b += __shfl_down(b, off, 64);
  }
  int lane = threadIdx.x & 63, wid = threadIdx.x >> 6;
  __syncthreads();
  if (lane == 0) { scratch[wid] = a; scratch[8 + wid] = b; }
  __syncthreads();
  float sa = 0.f, sb = 0.f;
#pragma unroll
  for (int i = 0; i < 8; i++) { sa += scratch[i]; sb += scratch[8 + i]; }
  a = sa; b = sb;
}

// ---------------- weight prep ----------------
template <int KT>
__global__ __launch_bounds__(256) void k_prepw_conv(const float* __restrict__ w,
                                                    __hip_bfloat16* __restrict__ wt) {
  __shared__ float l[512 * KT];
  int co = blockIdx.x;
  const float* wb = w + (size_t)co * 512 * KT;
  for (int i = threadIdx.x; i < 512 * KT; i += 256) l[i] = wb[i];
  __syncthreads();
  __hip_bfloat16* wo = wt + (size_t)co * 512 * KT;
  for (int i = threadIdx.x; i < 512 * KT; i += 256) {
    int kk = i >> 9, ci = i & 511;
    wo[i] = __float2bfloat16(l[ci * KT + kk]);
  }
}

template <int KD, int ND>
__global__ __launch_bounds__(256) void k_prepw_mlp(const float* __restrict__ w,
                                                   __hip_bfloat16* __restrict__ wt) {
  __shared__ float tile[32][33];
  int bx = blockIdx.x % (ND / 32);
  int by = blockIdx.x / (ND / 32);
  int tx = threadIdx.x & 31, ty = threadIdx.x >> 5;
#pragma unroll
  for (int i = 0; i < 32; i += 8)
    tile[ty + i][tx] = w[(size_t)(by * 32 + ty + i) * ND + bx * 32 + tx];
  __syncthreads();
#pragma unroll
  for (int i = 0; i < 32; i += 8)
    wt[(size_t)(bx * 32 + ty + i) * KD + by * 32 + tx] = __float2bfloat16(tile[tx][ty + i]);
}

// ---------------- conv0 + ChannelNorm + ReLU -> bf16 ----------------
__global__ __launch_bounds__(512) void k_conv0(const float* __restrict__ x, const float* __restrict__ w,
                                               const float* __restrict__ bias, const float* __restrict__ gw,
                                               const float* __restrict__ gb, __hip_bfloat16* __restrict__ out) {
  __shared__ float xv[48];
  __shared__ float tb[512 * 9];
  __shared__ float stats[16];
  int b = blockIdx.x / (T0 / 8);
  int t0 = (blockIdx.x % (T0 / 8)) * 8;
  int tid = threadIdx.x;
  if (tid < 45) xv[tid] = x[(size_t)b * LIN + refl(t0 * 5 - 3 + tid, LIN)];
  __syncthreads();
  float wk[10];
#pragma unroll
  for (int k = 0; k < 10; k++) wk[k] = w[tid * 10 + k];
  float bs = bias[tid];
  float acc[8];
#pragma unroll
  for (int tt = 0; tt < 8; tt++) {
    float a = bs;
#pragma unroll
    for (int k = 0; k < 10; k++) a += xv[tt * 5 + k] * wk[k];
    acc[tt] = a;
    tb[tid * 9 + tt] = a;
  }
  __syncthreads();
  int wave = tid >> 6, lane = tid & 63;
  float s = 0.f, q = 0.f;
#pragma unroll
  for (int j = 0; j < 8; j++) {
    float v = tb[(lane * 8 + j) * 9 + wave];
    s += v; q += v * v;
  }
#pragma unroll
  for (int off = 32; off > 0; off >>= 1) {
    s += __shfl_xor(s, off, 64);
    q += __shfl_xor(q, off, 64);
  }
  if (lane == 0) {
    float mean = s * (1.f / NC);
    float var = fmaxf((q - s * s * (1.f / NC)) * (1.f / (NC - 1)), 0.f);
    stats[wave] = mean;
    stats[8 + wave] = rsqrtf(var + EPSF);
  }
  __syncthreads();
  float gwv = gw[tid], gbv = gb[tid];
#pragma unroll
  for (int tt = 0; tt < 8; tt++) {
    float y = (acc[tt] - stats[tt]) * stats[8 + tt] * gwv + gbv;
    out[((size_t)(b * T0 + t0 + tt)) * NC + tid] = __float2bfloat16(fmaxf(y, 0.f));
  }
}

// ---------------- MFMA GEMM: 64x128 tile, BK=32, double-buffered, XOR-swizzled LDS ----
// 256 thr = 4 waves 2x2 (wave = 32x64). XCD swizzle + optional split-K.
// EPI 0: store raw fp32 partial to Cf + sk*MM*NN. EPI 1: +bias, exact GELU -> bf16.
template <int MODE, int TIN_, int TOUT_, int SS, int PP, int KK, int NN, int EPI, int SPLITK, int MM>
__global__ __launch_bounds__(256) void k_gemm(const __hip_bfloat16* __restrict__ A,
                                              const __hip_bfloat16* __restrict__ Bt,
                                              const float* __restrict__ bias,
                                              float* __restrict__ Cf,
                                              __hip_bfloat16* __restrict__ Cb) {
  __shared__ __align__(16) __hip_bfloat16 sA[2][64 * 32];
  __shared__ __align__(16) __hip_bfloat16 sB[2][128 * 32];
  const int tid = threadIdx.x;
  const int lane = tid & 63;
  const int wave = tid >> 6;
  const int wm = wave >> 1, wn = wave & 1;
  constexpr int nt = NN / 128;
  constexpr int PS = (MM / 512) * nt;  // slots per split (row-groups of 8 x col tiles)
  const int blk = blockIdx.x;
  const int xs = blk & 7, sl = blk >> 3;
  const int sk = sl / PS, rem = sl % PS;
  const int row0 = ((rem / nt) * 8 + xs) * 64;
  const int col0 = (rem % nt) * 128;
  constexpr int KB = (KK / SPLITK) / 32;
  const int kb0 = sk * KB, kb1 = kb0 + KB;
  const int cq = lane >> 4, cl = lane & 15;

  auto stage = [&](int kb, int buf) {
    {
      int m = tid >> 2, kc = tid & 3;
      int kcs = kc ^ (m & 3);  // XOR swizzle on global k-chunk
      size_t ga;
      if (MODE == 0) {
        ga = (size_t)(row0 + m) * KK + kb * 32 + kcs * 8;
      } else {
        int r = row0 + m;
        int bb = r / TOUT_;
        int t = r - bb * TOUT_;
        int k = (kb * 32) >> 9;
        int ci = ((kb * 32) & 511) + kcs * 8;
        int gt = refl(t * SS - PP + k, TIN_);
        ga = (((size_t)(bb * TIN_ + gt)) << 9) + ci;
      }
      gld16((char*)&sA[buf][0] + tid * 16, (const char*)(A + ga));
    }
#pragma unroll
    for (int rr = 0; rr < 2; rr++) {
      int c = rr * 256 + tid;
      int n = c >> 2, kc = c & 3;
      int kcs = kc ^ (n & 3);
      gld16((char*)&sB[buf][0] + c * 16, (const char*)(Bt + (size_t)(col0 + n) * KK + kb * 32 + kcs * 8));
    }
  };

  f32x4 acc[2][4];
  const f32x4 zz = {0.f, 0.f, 0.f, 0.f};
#pragma unroll
  for (int mi = 0; mi < 2; mi++)
#pragma unroll
    for (int ni = 0; ni < 4; ni++) acc[mi][ni] = zz;

  stage(kb0, 0);
  const int p = cq ^ (cl & 3);  // swizzled k-chunk position for reads
  for (int kb = kb0; kb < kb1; kb++) {
    int cur = (kb - kb0) & 1;
    __syncthreads();  // drains prefetch of `cur`; guards buffer reuse
    if (kb + 1 < kb1) stage(kb + 1, cur ^ 1);
    const short* bA = (const short*)&sA[cur][0];
    const short* bB = (const short*)&sB[cur][0];
    bf16x8 af[2], bfr[4];
#pragma unroll
    for (int mi = 0; mi < 2; mi++)
      af[mi] = *(const bf16x8*)(bA + (wm * 32 + mi * 16 + cl) * 32 + p * 8);
#pragma unroll
    for (int ni = 0; ni < 4; ni++)
      bfr[ni] = *(const bf16x8*)(bB + (wn * 64 + ni * 16 + cl) * 32 + p * 8);
#pragma unroll
    for (int mi = 0; mi < 2; mi++)
#pragma unroll
      for (int ni = 0; ni < 4; ni++)
        acc[mi][ni] = __builtin_amdgcn_mfma_f32_16x16x32_bf16(af[mi], bfr[ni], acc[mi][ni], 0, 0, 0);
  }

  // epilogue; C/D: col=lane&15, row=(lane>>4)*4+reg
#pragma unroll
  for (int mi = 0; mi < 2; mi++)
#pragma unroll
    for (int ni = 0; ni < 4; ni++)
#pragma unroll
      for (int r2 = 0; r2 < 4; r2++) {
        int row = row0 + wm * 32 + mi * 16 + cq * 4 + r2;
        int col = col0 + wn * 64 + ni * 16 + cl;
        float v = acc[mi][ni][r2];
        if (EPI == 1) {
          v += bias[col];
          v = 0.5f * v * (1.f + erff(v * 0.70710678118654752f));
          Cb[(size_t)row * NN + col] = __float2bfloat16(v);
        } else {
          Cf[(size_t)sk * MM * NN + (size_t)row * NN + col] = v;
        }
      }
}

// ---------------- ChannelNorm (+conv bias, sum NS split-K partials) + ReLU -> bf16 ----
template <int NS>
__global__ __launch_bounds__(512) void k_cnorm(const float* __restrict__ g, const float* __restrict__ cb,
                                               const float* __restrict__ gw, const float* __restrict__ gb,
                                               __hip_bfloat16* __restrict__ out, size_t stride) {
  int wave = threadIdx.x >> 6, lane = threadIdx.x & 63;
  size_t row = (size_t)blockIdx.x * 8 + wave;
  float v[8];
  {
    float4 c0 = *(const float4*)(cb + lane * 8), c1 = *(const float4*)(cb + lane * 8 + 4);
    v[0] = c0.x; v[1] = c0.y; v[2] = c0.z; v[3] = c0.w;
    v[4] = c1.x; v[5] = c1.y; v[6] = c1.z; v[7] = c1.w;
  }
#pragma unroll
  for (int s = 0; s < NS; s++) {
    const float* gr = g + s * stride + row * NC + lane * 8;
    float4 a0 = *(const float4*)gr;
    float4 a1 = *(const float4*)(gr + 4);
    v[0] += a0.x; v[1] += a0.y; v[2] += a0.z; v[3] += a0.w;
    v[4] += a1.x; v[5] += a1.y; v[6] += a1.z; v[7] += a1.w;
  }
  float s = 0.f, q = 0.f;
#pragma unroll
  for (int j = 0; j < 8; j++) { s += v[j]; q += v[j] * v[j]; }
#pragma unroll
  for (int off = 32; off > 0; off >>= 1) {
    s += __shfl_xor(s, off, 64);
    q += __shfl_xor(q, off, 64);
  }
  float mean = s * (1.f / NC);
  float var = fmaxf((q - s * s * (1.f / NC)) * (1.f / (NC - 1)), 0.f);
  float rstd = rsqrtf(var + EPSF);
  float4 w0 = *(const float4*)(gw + lane * 8), w1 = *(const float4*)(gw + lane * 8 + 4);
  float4 b0 = *(const float4*)(gb + lane * 8), b1 = *(const float4*)(gb + lane * 8 + 4);
  float gwv[8] = {w0.x, w0.y, w0.z, w0.w, w1.x, w1.y, w1.z, w1.w};
  float gbv[8] = {b0.x, b0.y, b0.z, b0.w, b1.x, b1.y, b1.z, b1.w};
  union { __hip_bfloat16 h[8]; uint4 u; } pk;
#pragma unroll
  for (int j = 0; j < 8; j++)
    pk.h[j] = __float2bfloat16(fmaxf((v[j] - mean) * rstd * gwv[j] + gbv[j], 0.f));
  *(uint4*)(out + row * NC + lane * 8) = pk.u;
}

// ---------------- head / cumsum / pool / final ----------------
__global__ __launch_bounds__(256) void k_head(const __hip_bfloat16* __restrict__ z, const float* __restrict__ w,
                                              const float* __restrict__ bias, float* __restrict__ imp) {
  __shared__ float red[4];
  int row = blockIdx.x, tid = threadIdx.x;
  float a = 0.f;
  for (int i = tid; i < DM; i += 256) a += __bfloat162float(z[(size_t)row * DM + i]) * w[i];
#pragma unroll
  for (int off = 32; off > 0; off >>= 1) a += __shfl_down(a, off, 64);
  int lane = tid & 63, wid = tid >> 6;
  if (lane == 0) red[wid] = a;
  __syncthreads();
  if (tid == 0) {
    float s = red[0] + red[1] + red[2] + red[3] + bias[0];
    imp[row] = 1.f / (1.f + expf(-s)) + TEMPF;
  }
}

__global__ __launch_bounds__(512) void k_cumsum(const float* __restrict__ imp, float* __restrict__ cs) {
  __shared__ float sc[T3];
  int b = blockIdx.x, tid = threadIdx.x;
  sc[tid] = imp[b * T3 + tid];
  __syncthreads();
  for (int off = 1; off < T3; off <<= 1) {
    float add = (tid >= off) ? sc[tid - off] : 0.f;
    __syncthreads();
    sc[tid] += add;
    __syncthreads();
  }
  float total = sc[T3 - 1];
  cs[b * T3 + tid] = sc[tid] * ((float)TN / total);
}

__device__ __forceinline__ float dfun(float cv, int n) {
  float d = fmaxf(cv - (float)n, 0.f);
  if (n < TN - 1) d = fminf(d, 1.f);
  return d;
}

__global__ __launch_bounds__(512) void k_pool(const __hip_bfloat16* __restrict__ f, const float* __restrict__ cs,
                                              float* __restrict__ pooled) {
  __shared__ float wt[T3];
  int b = blockIdx.x / TN, n = blockIdx.x % TN;
  int tid = threadIdx.x;
  {
    float c1 = cs[b * T3 + tid];
    float c0 = (tid > 0) ? cs[b * T3 + tid - 1] : 0.f;
    wt[tid] = dfun(c1, n) - dfun(c0, n);
  }
  __syncthreads();
  float acc = 0.f;
  for (int t = 0; t < T3; t++) {
    float w = wt[t];
    if (w != 0.f) acc += w * __bfloat162float(f[((size_t)b * T3 + t) * NC + tid]);
  }
  pooled[((size_t)b * TN + n) * NC + tid] = acc;
}

__global__ __launch_bounds__(512) void k_final(const float* __restrict__ pooled, const float* __restrict__ gw,
                                               const float* __restrict__ gb, float* __restrict__ out) {
  __shared__ float red[16];
  int b = blockIdx.x / TN, n = blockIdx.x % TN;
  int tid = threadIdx.x;
  float v = pooled[((size_t)b * TN + n) * NC + tid];
  float s = v, q = v * v;
  blk_sum2_512(s, q, red);
  float mean = s * (1.f / NC);
  float var = fmaxf((q - s * s * (1.f / NC)) * (1.f / (NC - 1)), 0.f);
  float y = (v - mean) * rsqrtf(var + EPSF) * gw[tid] + gb[tid];
  out[((size_t)b * NC + tid) * TN + n] = fmaxf(y, 0.f);
}

extern "C" void kernel_launch(void* const* d_in, const int* in_sizes, int n_in,
                              void* d_out, int out_size, void* d_ws, size_t ws_size,
                              hipStream_t stream) {
  const float* x   = (const float*)d_in[0];
  const float* c0w = (const float*)d_in[1];  const float* c0b = (const float*)d_in[2];
  const float* c1w = (const float*)d_in[3];  const float* c1b = (const float*)d_in[4];
  const float* c2w = (const float*)d_in[5];  const float* c2b = (const float*)d_in[6];
  const float* c3w = (const float*)d_in[7];  const float* c3b = (const float*)d_in[8];
  const float* mw1 = (const float*)d_in[9];  const float* mb1 = (const float*)d_in[10];
  const float* mw2 = (const float*)d_in[11]; const float* mb2 = (const float*)d_in[12];
  const float* mw3 = (const float*)d_in[13]; const float* mb3 = (const float*)d_in[14];
  const float* n0w = (const float*)d_in[15]; const float* n0b = (const float*)d_in[16];
  const float* n1w = (const float*)d_in[17]; const float* n1b = (const float*)d_in[18];
  const float* n2w = (const float*)d_in[19]; const float* n2b = (const float*)d_in[20];
  const float* n3w = (const float*)d_in[21]; const float* n3b = (const float*)d_in[22];
  const float* n4w = (const float*)d_in[23]; const float* n4b = (const float*)d_in[24];

  char* base = (char*)d_ws;
  __hip_bfloat16* h0b  = (__hip_bfloat16*)(base);                     // 32 MB [dead after conv1 gemm]
  float*          g    = (float*)(base + (32u << 20));                // 16 MB fp32 partials
  __hip_bfloat16* h1b  = (__hip_bfloat16*)(base + (48u << 20));       // 8 MB
  __hip_bfloat16* h2b  = (__hip_bfloat16*)(base + (56u << 20));       // 4 MB
  __hip_bfloat16* h3b  = (__hip_bfloat16*)(base + (60u << 20));       // 2 MB
  float*          pooled = (float*)(base + (62u << 20));              // 2 MB
  float*          imp  = (float*)(base + (64u << 20));                // 8 KB
  float*          cs   = (float*)(base + (64u << 20) + 8192);         // 8 KB
  __hip_bfloat16* wt1  = (__hip_bfloat16*)(base + (65u << 20));       // 4 MB
  __hip_bfloat16* wt2  = (__hip_bfloat16*)(base + (69u << 20));       // 2 MB
  __hip_bfloat16* wt3  = (__hip_bfloat16*)(base + (71u << 20));       // 2 MB
  __hip_bfloat16* wm1t = (__hip_bfloat16*)(base + (73u << 20));       // 2 MB
  __hip_bfloat16* wm2t = (__hip_bfloat16*)(base + (75u << 20));       // 8 MB
  __hip_bfloat16* z1b  = h0b;
  __hip_bfloat16* z2b  = (__hip_bfloat16*)(base + (8u << 20));
  float* outp = (float*)d_out;

  k_prepw_conv<8><<<512, 256, 0, stream>>>(c1w, wt1);
  k_prepw_conv<4><<<512, 256, 0, stream>>>(c2w, wt2);
  k_prepw_conv<4><<<512, 256, 0, stream>>>(c3w, wt3);
  k_prepw_mlp<512, 2048><<<(2048 / 32) * (512 / 32), 256, 0, stream>>>(mw1, wm1t);
  k_prepw_mlp<2048, 2048><<<(2048 / 32) * (2048 / 32), 256, 0, stream>>>(mw2, wm2t);

  k_conv0<<<NB * (T0 / 8), 512, 0, stream>>>(x, c0w, c0b, n0w, n0b, h0b);

  // conv1: M=8192, K=4096, N=512, SPLITK=1 -> 512 blocks
  k_gemm<1, 8192, 2048, 4, 2, 4096, 512, 0, 1, 8192><<<512, 256, 0, stream>>>(h0b, wt1, nullptr, g, nullptr);
  k_cnorm<1><<<8192 / 8, 512, 0, stream>>>(g, c1b, n1w, n1b, h1b, (size_t)8192 * 512);
  // conv2: M=4096, K=2048, SPLITK=2 -> 512 blocks
  k_gemm<1, 2048, 1024, 2, 1, 2048, 512, 0, 2, 4096><<<512, 256, 0, stream>>>(h1b, wt2, nullptr, g, nullptr);
  k_cnorm<2><<<4096 / 8, 512, 0, stream>>>(g, c2b, n2w, n2b, h2b, (size_t)4096 * 512);
  // conv3: M=2048, K=2048, SPLITK=4 -> 512 blocks
  k_gemm<1, 1024, 512, 2, 1, 2048, 512, 0, 4, 2048><<<512, 256, 0, stream>>>(h2b, wt3, nullptr, g, nullptr);
  k_cnorm<4><<<2048 / 8, 512, 0, stream>>>(g, c3b, n3w, n3b, h3b, (size_t)2048 * 512);

  // mlp1: M=2048, K=512, N=2048 -> 512 blocks
  k_gemm<0, 0, 1, 0, 0, 512, 2048, 1, 1, 2048><<<512, 256, 0, stream>>>(h3b, wm1t, mb1, nullptr, z1b);
  // mlp2: M=2048, K=2048, N=2048 -> 512 blocks
  k_gemm<0, 0, 1, 0, 0, 2048, 2048, 1, 1, 2048><<<512, 256, 0, stream>>>(z1b, wm2t, mb2, nullptr, z2b);

  k_head<<<NB * T3, 256, 0, stream>>>(z2b, mw3, mb3, imp);
  k_cumsum<<<NB, 512, 0, stream>>>(imp, cs);
  k_pool<<<NB * TN, 512, 0, stream>>>(h3b, cs, pooled);
  k_final<<<NB * TN, 512, 0, stream>>>(pooled, n4w, n4b, outp);
}

// Round 5
// 351.375 us; speedup vs baseline: 7.8613x; 1.0851x over previous
//
#include <hip/hip_runtime.h>
#include <hip/hip_bf16.h>
#include <math.h>

#define NB 4
#define LIN 40960
#define NC 512
#define T0 8192
#define T1 2048
#define T2 1024
#define T3 512
#define TN 256
#define DM 2048
#define EPSF 1e-5f
#define TEMPF 1e-5f

typedef __attribute__((ext_vector_type(8))) short bf16x8;
typedef __attribute__((ext_vector_type(4))) float f32x4;

__device__ __forceinline__ int refl(int t, int T) {
  if (t < 0) t = -t;
  if (t >= T) t = 2 * T - 2 - t;
  return t;
}

__device__ __forceinline__ void gld16(void* lds, const void* g) {
  __builtin_amdgcn_global_load_lds((const __attribute__((address_space(1))) unsigned int*)g,
                                   (__attribute__((address_space(3))) unsigned int*)lds, 16, 0, 0);
}

__device__ __forceinline__ void blk_sum2_512(float& a, float& b, float* scratch) {
#pragma unroll
  for (int off = 32; off > 0; off >>= 1) {
    a += __shfl_down(a, off, 64);
    b += __shfl_down(b, off, 64);
  }
  int lane = threadIdx.x & 63, wid = threadIdx.x >> 6;
  __syncthreads();
  if (lane == 0) { scratch[wid] = a; scratch[8 + wid] = b; }
  __syncthreads();
  float sa = 0.f, sb = 0.f;
#pragma unroll
  for (int i = 0; i < 8; i++) { sa += scratch[i]; sb += scratch[8 + i]; }
  a = sa; b = sb;
}

// ---------------- weight prep ----------------
template <int KT>
__global__ __launch_bounds__(256) void k_prepw_conv(const float* __restrict__ w,
                                                    __hip_bfloat16* __restrict__ wt) {
  __shared__ float l[512 * KT];
  int co = blockIdx.x;
  const float* wb = w + (size_t)co * 512 * KT;
  for (int i = threadIdx.x; i < 512 * KT; i += 256) l[i] = wb[i];
  __syncthreads();
  __hip_bfloat16* wo = wt + (size_t)co * 512 * KT;
  for (int i = threadIdx.x; i < 512 * KT; i += 256) {
    int kk = i >> 9, ci = i & 511;
    wo[i] = __float2bfloat16(l[ci * KT + kk]);
  }
}

template <int KD, int ND>
__global__ __launch_bounds__(256) void k_prepw_mlp(const float* __restrict__ w,
                                                   __hip_bfloat16* __restrict__ wt) {
  __shared__ float tile[32][33];
  int bx = blockIdx.x % (ND / 32);
  int by = blockIdx.x / (ND / 32);
  int tx = threadIdx.x & 31, ty = threadIdx.x >> 5;
#pragma unroll
  for (int i = 0; i < 32; i += 8)
    tile[ty + i][tx] = w[(size_t)(by * 32 + ty + i) * ND + bx * 32 + tx];
  __syncthreads();
#pragma unroll
  for (int i = 0; i < 32; i += 8)
    wt[(size_t)(bx * 32 + ty + i) * KD + by * 32 + tx] = __float2bfloat16(tile[tx][ty + i]);
}

// ---------------- conv0 + ChannelNorm + ReLU -> bf16 ----------------
__global__ __launch_bounds__(512) void k_conv0(const float* __restrict__ x, const float* __restrict__ w,
                                               const float* __restrict__ bias, const float* __restrict__ gw,
                                               const float* __restrict__ gb, __hip_bfloat16* __restrict__ out) {
  __shared__ float xv[48];
  __shared__ float tb[512 * 9];
  __shared__ float stats[16];
  int b = blockIdx.x / (T0 / 8);
  int t0 = (blockIdx.x % (T0 / 8)) * 8;
  int tid = threadIdx.x;
  if (tid < 45) xv[tid] = x[(size_t)b * LIN + refl(t0 * 5 - 3 + tid, LIN)];
  __syncthreads();
  float wk[10];
#pragma unroll
  for (int k = 0; k < 10; k++) wk[k] = w[tid * 10 + k];
  float bs = bias[tid];
  float acc[8];
#pragma unroll
  for (int tt = 0; tt < 8; tt++) {
    float a = bs;
#pragma unroll
    for (int k = 0; k < 10; k++) a += xv[tt * 5 + k] * wk[k];
    acc[tt] = a;
    tb[tid * 9 + tt] = a;
  }
  __syncthreads();
  int wave = tid >> 6, lane = tid & 63;
  float s = 0.f, q = 0.f;
#pragma unroll
  for (int j = 0; j < 8; j++) {
    float v = tb[(lane * 8 + j) * 9 + wave];
    s += v; q += v * v;
  }
#pragma unroll
  for (int off = 32; off > 0; off >>= 1) {
    s += __shfl_xor(s, off, 64);
    q += __shfl_xor(q, off, 64);
  }
  if (lane == 0) {
    float mean = s * (1.f / NC);
    float var = fmaxf((q - s * s * (1.f / NC)) * (1.f / (NC - 1)), 0.f);
    stats[wave] = mean;
    stats[8 + wave] = rsqrtf(var + EPSF);
  }
  __syncthreads();
  float gwv = gw[tid], gbv = gb[tid];
#pragma unroll
  for (int tt = 0; tt < 8; tt++) {
    float y = (acc[tt] - stats[tt]) * stats[8 + tt] * gwv + gbv;
    out[((size_t)(b * T0 + t0 + tt)) * NC + tid] = __float2bfloat16(fmaxf(y, 0.f));
  }
}

// ---------------- MFMA GEMM v2: 128x128 tile (m97 structure), BK=32, dbuf, split-K ----
// 256 thr = 4 waves 2x2, wave = 64x64 via 4x4 of 16x16x32. fp32 partials out.
template <int MODE, int TIN_, int TOUT_, int SS, int PP, int KK, int NN, int SPLITK, int MM>
__global__ __launch_bounds__(256) void k_gemm2(const __hip_bfloat16* __restrict__ A,
                                               const __hip_bfloat16* __restrict__ Bt,
                                               float* __restrict__ Cf) {
  __shared__ __align__(16) __hip_bfloat16 sA[2][128 * 32];
  __shared__ __align__(16) __hip_bfloat16 sB[2][128 * 32];
  const int tid = threadIdx.x;
  const int lane = tid & 63;
  const int wave = tid >> 6;
  const int wm = wave >> 1, wn = wave & 1;
  constexpr int nt = NN / 128;
  constexpr int PS = (MM / 1024) * nt;  // slots per split (8-row-tile groups x col tiles)
  const int blk = blockIdx.x;
  const int xs = blk & 7, sl = blk >> 3;
  const int sk = sl / PS, rem = sl % PS;
  const int row0 = ((rem / nt) * 8 + xs) * 128;
  const int col0 = (rem % nt) * 128;
  constexpr int KB = (KK / SPLITK) / 32;
  const int kb0 = sk * KB, kb1 = kb0 + KB;
  const int cq = lane >> 4, cl = lane & 15;

  auto stage = [&](int kb, int buf) {
#pragma unroll
    for (int rr = 0; rr < 2; rr++) {
      int c = rr * 256 + tid;
      int m = c >> 2, kc = c & 3;
      int kcs = kc ^ (m & 3);
      size_t ga;
      if (MODE == 0) {
        ga = (size_t)(row0 + m) * KK + kb * 32 + kcs * 8;
      } else {
        int r = row0 + m;
        int bb = r / TOUT_;
        int t = r - bb * TOUT_;
        int k = (kb * 32) >> 9;
        int ci = ((kb * 32) & 511) + kcs * 8;
        int gt = refl(t * SS - PP + k, TIN_);
        ga = (((size_t)(bb * TIN_ + gt)) << 9) + ci;
      }
      gld16((char*)&sA[buf][0] + c * 16, (const char*)(A + ga));
    }
#pragma unroll
    for (int rr = 0; rr < 2; rr++) {
      int c = rr * 256 + tid;
      int n = c >> 2, kc = c & 3;
      int kcs = kc ^ (n & 3);
      gld16((char*)&sB[buf][0] + c * 16, (const char*)(Bt + (size_t)(col0 + n) * KK + kb * 32 + kcs * 8));
    }
  };

  f32x4 acc[4][4];
  const f32x4 zz = {0.f, 0.f, 0.f, 0.f};
#pragma unroll
  for (int mi = 0; mi < 4; mi++)
#pragma unroll
    for (int ni = 0; ni < 4; ni++) acc[mi][ni] = zz;

  stage(kb0, 0);
  const int p = cq ^ (cl & 3);
  for (int kb = kb0; kb < kb1; kb++) {
    int cur = (kb - kb0) & 1;
    __syncthreads();
    if (kb + 1 < kb1) stage(kb + 1, cur ^ 1);
    const short* bA = (const short*)&sA[cur][0];
    const short* bB = (const short*)&sB[cur][0];
    bf16x8 af[4], bfr[4];
#pragma unroll
    for (int mi = 0; mi < 4; mi++)
      af[mi] = *(const bf16x8*)(bA + (wm * 64 + mi * 16 + cl) * 32 + p * 8);
#pragma unroll
    for (int ni = 0; ni < 4; ni++)
      bfr[ni] = *(const bf16x8*)(bB + (wn * 64 + ni * 16 + cl) * 32 + p * 8);
#pragma unroll
    for (int mi = 0; mi < 4; mi++)
#pragma unroll
      for (int ni = 0; ni < 4; ni++)
        acc[mi][ni] = __builtin_amdgcn_mfma_f32_16x16x32_bf16(af[mi], bfr[ni], acc[mi][ni], 0, 0, 0);
  }

  // C/D: col=lane&15, row=(lane>>4)*4+reg
#pragma unroll
  for (int mi = 0; mi < 4; mi++)
#pragma unroll
    for (int ni = 0; ni < 4; ni++)
#pragma unroll
      for (int r2 = 0; r2 < 4; r2++) {
        int row = row0 + wm * 64 + mi * 16 + cq * 4 + r2;
        int col = col0 + wn * 64 + ni * 16 + cl;
        Cf[(size_t)sk * MM * NN + (size_t)row * NN + col] = acc[mi][ni][r2];
      }
}

// ---------------- MFMA GEMM v1: 64x128 tile (for small shapes: conv3, mlp1) ----------
template <int MODE, int TIN_, int TOUT_, int SS, int PP, int KK, int NN, int EPI, int SPLITK, int MM>
__global__ __launch_bounds__(256) void k_gemm(const __hip_bfloat16* __restrict__ A,
                                              const __hip_bfloat16* __restrict__ Bt,
                                              const float* __restrict__ bias,
                                              float* __restrict__ Cf,
                                              __hip_bfloat16* __restrict__ Cb) {
  __shared__ __align__(16) __hip_bfloat16 sA[2][64 * 32];
  __shared__ __align__(16) __hip_bfloat16 sB[2][128 * 32];
  const int tid = threadIdx.x;
  const int lane = tid & 63;
  const int wave = tid >> 6;
  const int wm = wave >> 1, wn = wave & 1;
  constexpr int nt = NN / 128;
  constexpr int PS = (MM / 512) * nt;
  const int blk = blockIdx.x;
  const int xs = blk & 7, sl = blk >> 3;
  const int sk = sl / PS, rem = sl % PS;
  const int row0 = ((rem / nt) * 8 + xs) * 64;
  const int col0 = (rem % nt) * 128;
  constexpr int KB = (KK / SPLITK) / 32;
  const int kb0 = sk * KB, kb1 = kb0 + KB;
  const int cq = lane >> 4, cl = lane & 15;

  auto stage = [&](int kb, int buf) {
    {
      int m = tid >> 2, kc = tid & 3;
      int kcs = kc ^ (m & 3);
      size_t ga;
      if (MODE == 0) {
        ga = (size_t)(row0 + m) * KK + kb * 32 + kcs * 8;
      } else {
        int r = row0 + m;
        int bb = r / TOUT_;
        int t = r - bb * TOUT_;
        int k = (kb * 32) >> 9;
        int ci = ((kb * 32) & 511) + kcs * 8;
        int gt = refl(t * SS - PP + k, TIN_);
        ga = (((size_t)(bb * TIN_ + gt)) << 9) + ci;
      }
      gld16((char*)&sA[buf][0] + tid * 16, (const char*)(A + ga));
    }
#pragma unroll
    for (int rr = 0; rr < 2; rr++) {
      int c = rr * 256 + tid;
      int n = c >> 2, kc = c & 3;
      int kcs = kc ^ (n & 3);
      gld16((char*)&sB[buf][0] + c * 16, (const char*)(Bt + (size_t)(col0 + n) * KK + kb * 32 + kcs * 8));
    }
  };

  f32x4 acc[2][4];
  const f32x4 zz = {0.f, 0.f, 0.f, 0.f};
#pragma unroll
  for (int mi = 0; mi < 2; mi++)
#pragma unroll
    for (int ni = 0; ni < 4; ni++) acc[mi][ni] = zz;

  stage(kb0, 0);
  const int p = cq ^ (cl & 3);
  for (int kb = kb0; kb < kb1; kb++) {
    int cur = (kb - kb0) & 1;
    __syncthreads();
    if (kb + 1 < kb1) stage(kb + 1, cur ^ 1);
    const short* bA = (const short*)&sA[cur][0];
    const short* bB = (const short*)&sB[cur][0];
    bf16x8 af[2], bfr[4];
#pragma unroll
    for (int mi = 0; mi < 2; mi++)
      af[mi] = *(const bf16x8*)(bA + (wm * 32 + mi * 16 + cl) * 32 + p * 8);
#pragma unroll
    for (int ni = 0; ni < 4; ni++)
      bfr[ni] = *(const bf16x8*)(bB + (wn * 64 + ni * 16 + cl) * 32 + p * 8);
#pragma unroll
    for (int mi = 0; mi < 2; mi++)
#pragma unroll
      for (int ni = 0; ni < 4; ni++)
        acc[mi][ni] = __builtin_amdgcn_mfma_f32_16x16x32_bf16(af[mi], bfr[ni], acc[mi][ni], 0, 0, 0);
  }

#pragma unroll
  for (int mi = 0; mi < 2; mi++)
#pragma unroll
    for (int ni = 0; ni < 4; ni++)
#pragma unroll
      for (int r2 = 0; r2 < 4; r2++) {
        int row = row0 + wm * 32 + mi * 16 + cq * 4 + r2;
        int col = col0 + wn * 64 + ni * 16 + cl;
        float v = acc[mi][ni][r2];
        if (EPI == 1) {
          v += bias[col];
          v = 0.5f * v * (1.f + erff(v * 0.70710678118654752f));
          Cb[(size_t)row * NN + col] = __float2bfloat16(v);
        } else {
          Cf[(size_t)sk * MM * NN + (size_t)row * NN + col] = v;
        }
      }
}

// ---------------- ChannelNorm (+conv bias, sum NS split-K partials) + ReLU -> bf16 ----
template <int NS>
__global__ __launch_bounds__(512) void k_cnorm(const float* __restrict__ g, const float* __restrict__ cb,
                                               const float* __restrict__ gw, const float* __restrict__ gb,
                                               __hip_bfloat16* __restrict__ out, size_t stride) {
  int wave = threadIdx.x >> 6, lane = threadIdx.x & 63;
  size_t row = (size_t)blockIdx.x * 8 + wave;
  float v[8];
  {
    float4 c0 = *(const float4*)(cb + lane * 8), c1 = *(const float4*)(cb + lane * 8 + 4);
    v[0] = c0.x; v[1] = c0.y; v[2] = c0.z; v[3] = c0.w;
    v[4] = c1.x; v[5] = c1.y; v[6] = c1.z; v[7] = c1.w;
  }
#pragma unroll
  for (int s = 0; s < NS; s++) {
    const float* gr = g + s * stride + row * NC + lane * 8;
    float4 a0 = *(const float4*)gr;
    float4 a1 = *(const float4*)(gr + 4);
    v[0] += a0.x; v[1] += a0.y; v[2] += a0.z; v[3] += a0.w;
    v[4] += a1.x; v[5] += a1.y; v[6] += a1.z; v[7] += a1.w;
  }
  float s = 0.f, q = 0.f;
#pragma unroll
  for (int j = 0; j < 8; j++) { s += v[j]; q += v[j] * v[j]; }
#pragma unroll
  for (int off = 32; off > 0; off >>= 1) {
    s += __shfl_xor(s, off, 64);
    q += __shfl_xor(q, off, 64);
  }
  float mean = s * (1.f / NC);
  float var = fmaxf((q - s * s * (1.f / NC)) * (1.f / (NC - 1)), 0.f);
  float rstd = rsqrtf(var + EPSF);
  float4 w0 = *(const float4*)(gw + lane * 8), w1 = *(const float4*)(gw + lane * 8 + 4);
  float4 b0 = *(const float4*)(gb + lane * 8), b1 = *(const float4*)(gb + lane * 8 + 4);
  float gwv[8] = {w0.x, w0.y, w0.z, w0.w, w1.x, w1.y, w1.z, w1.w};
  float gbv[8] = {b0.x, b0.y, b0.z, b0.w, b1.x, b1.y, b1.z, b1.w};
  union { __hip_bfloat16 h[8]; uint4 u; } pk;
#pragma unroll
  for (int j = 0; j < 8; j++)
    pk.h[j] = __float2bfloat16(fmaxf((v[j] - mean) * rstd * gwv[j] + gbv[j], 0.f));
  *(uint4*)(out + row * NC + lane * 8) = pk.u;
}

// ---------------- sum NS mlp2 partials + bias + exact GELU -> bf16 ----------------
template <int NS>
__global__ __launch_bounds__(512) void k_gelu_red(const float* __restrict__ g, const float* __restrict__ bias,
                                                  __hip_bfloat16* __restrict__ out) {
  size_t base = ((size_t)blockIdx.x * 512 + threadIdx.x) * 8;
  int col = (int)(base & (DM - 1));
  float v[8];
  {
    float4 b0 = *(const float4*)(bias + col), b1 = *(const float4*)(bias + col + 4);
    v[0] = b0.x; v[1] = b0.y; v[2] = b0.z; v[3] = b0.w;
    v[4] = b1.x; v[5] = b1.y; v[6] = b1.z; v[7] = b1.w;
  }
#pragma unroll
  for (int s = 0; s < NS; s++) {
    const float* gr = g + (size_t)s * (2048 * 2048) + base;
    float4 a0 = *(const float4*)gr;
    float4 a1 = *(const float4*)(gr + 4);
    v[0] += a0.x; v[1] += a0.y; v[2] += a0.z; v[3] += a0.w;
    v[4] += a1.x; v[5] += a1.y; v[6] += a1.z; v[7] += a1.w;
  }
  union { __hip_bfloat16 h[8]; uint4 u; } pk;
#pragma unroll
  for (int j = 0; j < 8; j++) {
    float z = 0.5f * v[j] * (1.f + erff(v[j] * 0.70710678118654752f));
    pk.h[j] = __float2bfloat16(z);
  }
  *(uint4*)(out + base) = pk.u;
}

// ---------------- head: sigmoid(z @ w3 + b3) + TEMP ----------------
__global__ __launch_bounds__(256) void k_head(const __hip_bfloat16* __restrict__ z, const float* __restrict__ w,
                                              const float* __restrict__ bias, float* __restrict__ imp) {
  __shared__ float red[4];
  int row = blockIdx.x, tid = threadIdx.x;
  float a = 0.f;
  for (int i = tid; i < DM; i += 256) a += __bfloat162float(z[(size_t)row * DM + i]) * w[i];
#pragma unroll
  for (int off = 32; off > 0; off >>= 1) a += __shfl_down(a, off, 64);
  int lane = tid & 63, wid = tid >> 6;
  if (lane == 0) red[wid] = a;
  __syncthreads();
  if (tid == 0) {
    float s = red[0] + red[1] + red[2] + red[3] + bias[0];
    imp[row] = 1.f / (1.f + expf(-s)) + TEMPF;
  }
}

// ---------------- cumsum: 1 block, 4 waves (one per batch), barrier-free ----------
__global__ __launch_bounds__(256) void k_cumsum(const float* __restrict__ imp, float* __restrict__ cs) {
  int wave = threadIdx.x >> 6, lane = threadIdx.x & 63;
  const float* ib = imp + wave * T3 + lane * 8;
  float p[8];
  float run = 0.f;
#pragma unroll
  for (int j = 0; j < 8; j++) { run += ib[j]; p[j] = run; }
  float ls = run, s = ls;
#pragma unroll
  for (int off = 1; off < 64; off <<= 1) {
    float t = __shfl_up(s, off, 64);
    if (lane >= off) s += t;
  }
  float excl = s - ls;
  float total = __shfl(s, 63, 64);
  float scale = (float)TN / total;
  float* ob = cs + wave * T3 + lane * 8;
#pragma unroll
  for (int j = 0; j < 8; j++) ob[j] = (excl + p[j]) * scale;
}

__device__ __forceinline__ float dfun(float cv, int n) {
  float d = fmaxf(cv - (float)n, 0.f);
  if (n < TN - 1) d = fminf(d, 1.f);
  return d;
}

// ---------------- fused pool + final ChannelNorm + ReLU, write [B][C][TN] ----------
__global__ __launch_bounds__(512) void k_poolfinal(const __hip_bfloat16* __restrict__ f,
                                                   const float* __restrict__ cs,
                                                   const float* __restrict__ gw, const float* __restrict__ gb,
                                                   float* __restrict__ out) {
  __shared__ float wt[T3];
  __shared__ float red[16];
  int b = blockIdx.x / TN, n = blockIdx.x % TN;
  int tid = threadIdx.x;
  {
    float c1 = cs[b * T3 + tid];
    float c0 = (tid > 0) ? cs[b * T3 + tid - 1] : 0.f;
    wt[tid] = dfun(c1, n) - dfun(c0, n);
  }
  __syncthreads();
  float acc = 0.f;
  for (int t = 0; t < T3; t++) {
    float w = wt[t];
    if (w != 0.f) acc += w * __bfloat162float(f[((size_t)b * T3 + t) * NC + tid]);
  }
  float s = acc, q = acc * acc;
  blk_sum2_512(s, q, red);
  float mean = s * (1.f / NC);
  float var = fmaxf((q - s * s * (1.f / NC)) * (1.f / (NC - 1)), 0.f);
  float y = (acc - mean) * rsqrtf(var + EPSF) * gw[tid] + gb[tid];
  out[((size_t)b * NC + tid) * TN + n] = fmaxf(y, 0.f);
}

extern "C" void kernel_launch(void* const* d_in, const int* in_sizes, int n_in,
                              void* d_out, int out_size, void* d_ws, size_t ws_size,
                              hipStream_t stream) {
  const float* x   = (const float*)d_in[0];
  const float* c0w = (const float*)d_in[1];  const float* c0b = (const float*)d_in[2];
  const float* c1w = (const float*)d_in[3];  const float* c1b = (const float*)d_in[4];
  const float* c2w = (const float*)d_in[5];  const float* c2b = (const float*)d_in[6];
  const float* c3w = (const float*)d_in[7];  const float* c3b = (const float*)d_in[8];
  const float* mw1 = (const float*)d_in[9];  const float* mb1 = (const float*)d_in[10];
  const float* mw2 = (const float*)d_in[11]; const float* mb2 = (const float*)d_in[12];
  const float* mw3 = (const float*)d_in[13]; const float* mb3 = (const float*)d_in[14];
  const float* n0w = (const float*)d_in[15]; const float* n0b = (const float*)d_in[16];
  const float* n1w = (const float*)d_in[17]; const float* n1b = (const float*)d_in[18];
  const float* n2w = (const float*)d_in[19]; const float* n2b = (const float*)d_in[20];
  const float* n3w = (const float*)d_in[21]; const float* n3b = (const float*)d_in[22];
  const float* n4w = (const float*)d_in[23]; const float* n4b = (const float*)d_in[24];

  char* base = (char*)d_ws;
  // Workspace map (bytes). Total 97 MB (harness ws >= ~98.5 MB per round-0 usage).
  __hip_bfloat16* h0b  = (__hip_bfloat16*)(base);                     // [0,32M) conv0 out; dead after conv1
  float*          g    = (float*)(base + (32u << 20));                // [32M,64M) fp32 split-K partials
  __hip_bfloat16* h1b  = (__hip_bfloat16*)(base + (64u << 20));       // 8 MB
  __hip_bfloat16* h2b  = (__hip_bfloat16*)(base + (72u << 20));       // 4 MB
  __hip_bfloat16* h3b  = (__hip_bfloat16*)(base + (76u << 20));       // 2 MB
  float*          imp  = (float*)(base + (78u << 20));                // 8 KB
  float*          cs   = (float*)(base + (78u << 20) + 8192);         // 8 KB
  __hip_bfloat16* wt1  = (__hip_bfloat16*)(base + (79u << 20));       // 4 MB
  __hip_bfloat16* wt2  = (__hip_bfloat16*)(base + (83u << 20));       // 2 MB
  __hip_bfloat16* wt3  = (__hip_bfloat16*)(base + (85u << 20));       // 2 MB
  __hip_bfloat16* wm1t = (__hip_bfloat16*)(base + (87u << 20));       // 2 MB
  __hip_bfloat16* wm2t = (__hip_bfloat16*)(base + (89u << 20));       // 8 MB -> ends 97 MB
  __hip_bfloat16* z1b  = h0b;                                         // [0,8M)
  __hip_bfloat16* z2b  = (__hip_bfloat16*)(base + (8u << 20));        // [8M,16M)
  float* outp = (float*)d_out;

  k_prepw_conv<8><<<512, 256, 0, stream>>>(c1w, wt1);
  k_prepw_conv<4><<<512, 256, 0, stream>>>(c2w, wt2);
  k_prepw_conv<4><<<512, 256, 0, stream>>>(c3w, wt3);
  k_prepw_mlp<512, 2048><<<(2048 / 32) * (512 / 32), 256, 0, stream>>>(mw1, wm1t);
  k_prepw_mlp<2048, 2048><<<(2048 / 32) * (2048 / 32), 256, 0, stream>>>(mw2, wm2t);

  k_conv0<<<NB * (T0 / 8), 512, 0, stream>>>(x, c0w, c0b, n0w, n0b, h0b);

  // conv1: M=8192, K=4096, N=512, 128x128 tiles, SK2 -> 512 blocks
  k_gemm2<1, 8192, 2048, 4, 2, 4096, 512, 2, 8192><<<512, 256, 0, stream>>>(h0b, wt1, g);
  k_cnorm<2><<<8192 / 8, 512, 0, stream>>>(g, c1b, n1w, n1b, h1b, (size_t)8192 * 512);
  // conv2: M=4096, K=2048, 128x128, SK4 -> 512 blocks
  k_gemm2<1, 2048, 1024, 2, 1, 2048, 512, 4, 4096><<<512, 256, 0, stream>>>(h1b, wt2, g);
  k_cnorm<4><<<4096 / 8, 512, 0, stream>>>(g, c2b, n2w, n2b, h2b, (size_t)4096 * 512);
  // conv3: M=2048, K=2048, 64x128, SK4 -> 512 blocks
  k_gemm<1, 1024, 512, 2, 1, 2048, 512, 0, 4, 2048><<<512, 256, 0, stream>>>(h2b, wt3, nullptr, g, nullptr);
  k_cnorm<4><<<2048 / 8, 512, 0, stream>>>(g, c3b, n3w, n3b, h3b, (size_t)2048 * 512);

  // mlp1: M=2048, K=512, N=2048, 64x128 EPI=GELU -> 512 blocks
  k_gemm<0, 0, 1, 0, 0, 512, 2048, 1, 1, 2048><<<512, 256, 0, stream>>>(h3b, wm1t, mb1, nullptr, z1b);
  // mlp2: M=2048, K=2048, N=2048, 128x128, SK2 -> 512 blocks; then bias+GELU reduce
  k_gemm2<0, 0, 1, 0, 0, 2048, 2048, 2, 2048><<<512, 256, 0, stream>>>(z1b, wm2t, g);
  k_gelu_red<2><<<(2048 * 2048) / (512 * 8), 512, 0, stream>>>(g, mb2, z2b);

  k_head<<<NB * T3, 256, 0, stream>>>(z2b, mw3, mb3, imp);
  k_cumsum<<<1, 256, 0, stream>>>(imp, cs);
  k_poolfinal<<<NB * TN, 512, 0, stream>>>(h3b, cs, n4w, n4b, outp);
}

// Round 6
// 343.787 us; speedup vs baseline: 8.0349x; 1.0221x over previous
//
#include <hip/hip_runtime.h>
#include <hip/hip_bf16.h>
#include <math.h>

#define NB 4
#define LIN 40960
#define NC 512
#define T0 8192
#define T1 2048
#define T2 1024
#define T3 512
#define TN 256
#define DM 2048
#define EPSF 1e-5f
#define TEMPF 1e-5f

typedef __attribute__((ext_vector_type(8))) short bf16x8;
typedef __attribute__((ext_vector_type(4))) float f32x4;

__device__ __forceinline__ int refl(int t, int T) {
  if (t < 0) t = -t;
  if (t >= T) t = 2 * T - 2 - t;
  return t;
}

__device__ __forceinline__ void gld16(void* lds, const void* g) {
  __builtin_amdgcn_global_load_lds((const __attribute__((address_space(1))) unsigned int*)g,
                                   (__attribute__((address_space(3))) unsigned int*)lds, 16, 0, 0);
}

__device__ __forceinline__ void blk_sum2_512(float& a, float& b, float* scratch) {
#pragma unroll
  for (int off = 32; off > 0; off >>= 1) {
    a += __shfl_down(a, off, 64);
    b += __shfl_down(b, off, 64);
  }
  int lane = threadIdx.x & 63, wid = threadIdx.x >> 6;
  __syncthreads();
  if (lane == 0) { scratch[wid] = a; scratch[8 + wid] = b; }
  __syncthreads();
  float sa = 0.f, sb = 0.f;
#pragma unroll
  for (int i = 0; i < 8; i++) { sa += scratch[i]; sb += scratch[8 + i]; }
  a = sa; b = sb;
}

// ---------------- weight prep (merged) ----------------
template <int KT>
__device__ __forceinline__ void prep_conv_body(const float* __restrict__ w, __hip_bfloat16* __restrict__ wt,
                                               int co, float* l) {
  const float* wb = w + (size_t)co * 512 * KT;
  for (int i = threadIdx.x; i < 512 * KT; i += 256) l[i] = wb[i];
  __syncthreads();
  __hip_bfloat16* wo = wt + (size_t)co * 512 * KT;
  for (int i = threadIdx.x; i < 512 * KT; i += 256) {
    int kk = i >> 9, ci = i & 511;
    wo[i] = __float2bfloat16(l[ci * KT + kk]);
  }
}

template <int KD, int ND>
__device__ __forceinline__ void prep_mlp_body(const float* __restrict__ w, __hip_bfloat16* __restrict__ wt,
                                              int bidx, float* sbuf) {
  float(*tile)[33] = (float(*)[33])sbuf;
  int bx = bidx % (ND / 32);
  int by = bidx / (ND / 32);
  int tx = threadIdx.x & 31, ty = threadIdx.x >> 5;
#pragma unroll
  for (int i = 0; i < 32; i += 8)
    tile[ty + i][tx] = w[(size_t)(by * 32 + ty + i) * ND + bx * 32 + tx];
  __syncthreads();
#pragma unroll
  for (int i = 0; i < 32; i += 8)
    wt[(size_t)(bx * 32 + ty + i) * KD + by * 32 + tx] = __float2bfloat16(tile[tx][ty + i]);
}

// prepA: wt1(conv1), wt2, wt3, wm1t — 512+512+512+1024 = 2560 blocks
__global__ __launch_bounds__(256) void k_prepA(const float* c1w, const float* c2w, const float* c3w,
                                               const float* mw1, __hip_bfloat16* wt1, __hip_bfloat16* wt2,
                                               __hip_bfloat16* wt3, __hip_bfloat16* wm1t) {
  __shared__ float sb[4096];
  int b = blockIdx.x;
  if (b < 512) prep_conv_body<8>(c1w, wt1, b, sb);
  else if (b < 1024) prep_conv_body<4>(c2w, wt2, b - 512, sb);
  else if (b < 1536) prep_conv_body<4>(c3w, wt3, b - 1024, sb);
  else prep_mlp_body<512, 2048>(mw1, wm1t, b - 1536, sb);
}

// prepB: wm2t (deferred; overwrites dead wt1 region) — 4096 blocks
__global__ __launch_bounds__(256) void k_prepB(const float* mw2, __hip_bfloat16* wm2t) {
  __shared__ float sb[1056];
  prep_mlp_body<2048, 2048>(mw2, wm2t, blockIdx.x, sb);
}

// ---------------- conv0 + ChannelNorm + ReLU -> bf16 ----------------
__global__ __launch_bounds__(512) void k_conv0(const float* __restrict__ x, const float* __restrict__ w,
                                               const float* __restrict__ bias, const float* __restrict__ gw,
                                               const float* __restrict__ gb, __hip_bfloat16* __restrict__ out) {
  __shared__ float xv[48];
  __shared__ float tb[512 * 9];
  __shared__ float stats[16];
  int b = blockIdx.x / (T0 / 8);
  int t0 = (blockIdx.x % (T0 / 8)) * 8;
  int tid = threadIdx.x;
  if (tid < 45) xv[tid] = x[(size_t)b * LIN + refl(t0 * 5 - 3 + tid, LIN)];
  __syncthreads();
  float wk[10];
#pragma unroll
  for (int k = 0; k < 10; k++) wk[k] = w[tid * 10 + k];
  float bs = bias[tid];
  float acc[8];
#pragma unroll
  for (int tt = 0; tt < 8; tt++) {
    float a = bs;
#pragma unroll
    for (int k = 0; k < 10; k++) a += xv[tt * 5 + k] * wk[k];
    acc[tt] = a;
    tb[tid * 9 + tt] = a;
  }
  __syncthreads();
  int wave = tid >> 6, lane = tid & 63;
  float s = 0.f, q = 0.f;
#pragma unroll
  for (int j = 0; j < 8; j++) {
    float v = tb[(lane * 8 + j) * 9 + wave];
    s += v; q += v * v;
  }
#pragma unroll
  for (int off = 32; off > 0; off >>= 1) {
    s += __shfl_xor(s, off, 64);
    q += __shfl_xor(q, off, 64);
  }
  if (lane == 0) {
    float mean = s * (1.f / NC);
    float var = fmaxf((q - s * s * (1.f / NC)) * (1.f / (NC - 1)), 0.f);
    stats[wave] = mean;
    stats[8 + wave] = rsqrtf(var + EPSF);
  }
  __syncthreads();
  float gwv = gw[tid], gbv = gb[tid];
#pragma unroll
  for (int tt = 0; tt < 8; tt++) {
    float y = (acc[tt] - stats[tt]) * stats[8 + tt] * gwv + gbv;
    out[((size_t)(b * T0 + t0 + tt)) * NC + tid] = __float2bfloat16(fmaxf(y, 0.f));
  }
}

// ---------------- MFMA GEMM v2: 128x128 tile, BK=32, dbuf, non-uniform split-K ----
template <int MODE, int TIN_, int TOUT_, int SS, int PP, int KK, int NN, int SPLITK, int MM>
__global__ __launch_bounds__(256) void k_gemm2(const __hip_bfloat16* __restrict__ A,
                                               const __hip_bfloat16* __restrict__ Bt,
                                               float* __restrict__ Cf) {
  __shared__ __align__(16) __hip_bfloat16 sA[2][128 * 32];
  __shared__ __align__(16) __hip_bfloat16 sB[2][128 * 32];
  const int tid = threadIdx.x;
  const int lane = tid & 63;
  const int wave = tid >> 6;
  const int wm = wave >> 1, wn = wave & 1;
  constexpr int nt = NN / 128;
  constexpr int PS = (MM / 1024) * nt;
  constexpr int KBT = KK / 32;
  const int blk = blockIdx.x;
  const int xs = blk & 7, sl = blk >> 3;
  const int sk = sl / PS, rem = sl % PS;
  const int row0 = ((rem / nt) * 8 + xs) * 128;
  const int col0 = (rem % nt) * 128;
  const int kb0 = (sk * KBT) / SPLITK, kb1 = ((sk + 1) * KBT) / SPLITK;
  const int cq = lane >> 4, cl = lane & 15;

  auto stage = [&](int kb, int buf) {
#pragma unroll
    for (int rr = 0; rr < 2; rr++) {
      int c = rr * 256 + tid;
      int m = c >> 2, kc = c & 3;
      int kcs = kc ^ (m & 3);
      size_t ga;
      if (MODE == 0) {
        ga = (size_t)(row0 + m) * KK + kb * 32 + kcs * 8;
      } else {
        int r = row0 + m;
        int bb = r / TOUT_;
        int t = r - bb * TOUT_;
        int k = (kb * 32) >> 9;
        int ci = ((kb * 32) & 511) + kcs * 8;
        int gt = refl(t * SS - PP + k, TIN_);
        ga = (((size_t)(bb * TIN_ + gt)) << 9) + ci;
      }
      gld16((char*)&sA[buf][0] + c * 16, (const char*)(A + ga));
    }
#pragma unroll
    for (int rr = 0; rr < 2; rr++) {
      int c = rr * 256 + tid;
      int n = c >> 2, kc = c & 3;
      int kcs = kc ^ (n & 3);
      gld16((char*)&sB[buf][0] + c * 16, (const char*)(Bt + (size_t)(col0 + n) * KK + kb * 32 + kcs * 8));
    }
  };

  f32x4 acc[4][4];
  const f32x4 zz = {0.f, 0.f, 0.f, 0.f};
#pragma unroll
  for (int mi = 0; mi < 4; mi++)
#pragma unroll
    for (int ni = 0; ni < 4; ni++) acc[mi][ni] = zz;

  stage(kb0, 0);
  const int p = cq ^ (cl & 3);
  for (int kb = kb0; kb < kb1; kb++) {
    int cur = (kb - kb0) & 1;
    __syncthreads();
    if (kb + 1 < kb1) stage(kb + 1, cur ^ 1);
    const short* bA = (const short*)&sA[cur][0];
    const short* bB = (const short*)&sB[cur][0];
    bf16x8 af[4], bfr[4];
#pragma unroll
    for (int mi = 0; mi < 4; mi++)
      af[mi] = *(const bf16x8*)(bA + (wm * 64 + mi * 16 + cl) * 32 + p * 8);
#pragma unroll
    for (int ni = 0; ni < 4; ni++)
      bfr[ni] = *(const bf16x8*)(bB + (wn * 64 + ni * 16 + cl) * 32 + p * 8);
#pragma unroll
    for (int mi = 0; mi < 4; mi++)
#pragma unroll
      for (int ni = 0; ni < 4; ni++)
        acc[mi][ni] = __builtin_amdgcn_mfma_f32_16x16x32_bf16(af[mi], bfr[ni], acc[mi][ni], 0, 0, 0);
  }

  // C/D: col=lane&15, row=(lane>>4)*4+reg
#pragma unroll
  for (int mi = 0; mi < 4; mi++)
#pragma unroll
    for (int ni = 0; ni < 4; ni++)
#pragma unroll
      for (int r2 = 0; r2 < 4; r2++) {
        int row = row0 + wm * 64 + mi * 16 + cq * 4 + r2;
        int col = col0 + wn * 64 + ni * 16 + cl;
        Cf[(size_t)sk * MM * NN + (size_t)row * NN + col] = acc[mi][ni][r2];
      }
}

// ---------------- MFMA GEMM v1: 64x128 tile (conv3, mlp1) ----------
template <int MODE, int TIN_, int TOUT_, int SS, int PP, int KK, int NN, int EPI, int SPLITK, int MM>
__global__ __launch_bounds__(256) void k_gemm(const __hip_bfloat16* __restrict__ A,
                                              const __hip_bfloat16* __restrict__ Bt,
                                              const float* __restrict__ bias,
                                              float* __restrict__ Cf,
                                              __hip_bfloat16* __restrict__ Cb) {
  __shared__ __align__(16) __hip_bfloat16 sA[2][64 * 32];
  __shared__ __align__(16) __hip_bfloat16 sB[2][128 * 32];
  const int tid = threadIdx.x;
  const int lane = tid & 63;
  const int wave = tid >> 6;
  const int wm = wave >> 1, wn = wave & 1;
  constexpr int nt = NN / 128;
  constexpr int PS = (MM / 512) * nt;
  constexpr int KBT = KK / 32;
  const int blk = blockIdx.x;
  const int xs = blk & 7, sl = blk >> 3;
  const int sk = sl / PS, rem = sl % PS;
  const int row0 = ((rem / nt) * 8 + xs) * 64;
  const int col0 = (rem % nt) * 128;
  const int kb0 = (sk * KBT) / SPLITK, kb1 = ((sk + 1) * KBT) / SPLITK;
  const int cq = lane >> 4, cl = lane & 15;

  auto stage = [&](int kb, int buf) {
    {
      int m = tid >> 2, kc = tid & 3;
      int kcs = kc ^ (m & 3);
      size_t ga;
      if (MODE == 0) {
        ga = (size_t)(row0 + m) * KK + kb * 32 + kcs * 8;
      } else {
        int r = row0 + m;
        int bb = r / TOUT_;
        int t = r - bb * TOUT_;
        int k = (kb * 32) >> 9;
        int ci = ((kb * 32) & 511) + kcs * 8;
        int gt = refl(t * SS - PP + k, TIN_);
        ga = (((size_t)(bb * TIN_ + gt)) << 9) + ci;
      }
      gld16((char*)&sA[buf][0] + tid * 16, (const char*)(A + ga));
    }
#pragma unroll
    for (int rr = 0; rr < 2; rr++) {
      int c = rr * 256 + tid;
      int n = c >> 2, kc = c & 3;
      int kcs = kc ^ (n & 3);
      gld16((char*)&sB[buf][0] + c * 16, (const char*)(Bt + (size_t)(col0 + n) * KK + kb * 32 + kcs * 8));
    }
  };

  f32x4 acc[2][4];
  const f32x4 zz = {0.f, 0.f, 0.f, 0.f};
#pragma unroll
  for (int mi = 0; mi < 2; mi++)
#pragma unroll
    for (int ni = 0; ni < 4; ni++) acc[mi][ni] = zz;

  stage(kb0, 0);
  const int p = cq ^ (cl & 3);
  for (int kb = kb0; kb < kb1; kb++) {
    int cur = (kb - kb0) & 1;
    __syncthreads();
    if (kb + 1 < kb1) stage(kb + 1, cur ^ 1);
    const short* bA = (const short*)&sA[cur][0];
    const short* bB = (const short*)&sB[cur][0];
    bf16x8 af[2], bfr[4];
#pragma unroll
    for (int mi = 0; mi < 2; mi++)
      af[mi] = *(const bf16x8*)(bA + (wm * 32 + mi * 16 + cl) * 32 + p * 8);
#pragma unroll
    for (int ni = 0; ni < 4; ni++)
      bfr[ni] = *(const bf16x8*)(bB + (wn * 64 + ni * 16 + cl) * 32 + p * 8);
#pragma unroll
    for (int mi = 0; mi < 2; mi++)
#pragma unroll
      for (int ni = 0; ni < 4; ni++)
        acc[mi][ni] = __builtin_amdgcn_mfma_f32_16x16x32_bf16(af[mi], bfr[ni], acc[mi][ni], 0, 0, 0);
  }

#pragma unroll
  for (int mi = 0; mi < 2; mi++)
#pragma unroll
    for (int ni = 0; ni < 4; ni++)
#pragma unroll
      for (int r2 = 0; r2 < 4; r2++) {
        int row = row0 + wm * 32 + mi * 16 + cq * 4 + r2;
        int col = col0 + wn * 64 + ni * 16 + cl;
        float v = acc[mi][ni][r2];
        if (EPI == 1) {
          v += bias[col];
          v = 0.5f * v * (1.f + erff(v * 0.70710678118654752f));
          Cb[(size_t)row * NN + col] = __float2bfloat16(v);
        } else {
          Cf[(size_t)sk * MM * NN + (size_t)row * NN + col] = v;
        }
      }
}

// ---------------- ChannelNorm (+conv bias, sum NS split-K partials) + ReLU -> bf16 ----
template <int NS>
__global__ __launch_bounds__(512) void k_cnorm(const float* __restrict__ g, const float* __restrict__ cb,
                                               const float* __restrict__ gw, const float* __restrict__ gb,
                                               __hip_bfloat16* __restrict__ out, size_t stride) {
  int wave = threadIdx.x >> 6, lane = threadIdx.x & 63;
  size_t row = (size_t)blockIdx.x * 8 + wave;
  float v[8];
  {
    float4 c0 = *(const float4*)(cb + lane * 8), c1 = *(const float4*)(cb + lane * 8 + 4);
    v[0] = c0.x; v[1] = c0.y; v[2] = c0.z; v[3] = c0.w;
    v[4] = c1.x; v[5] = c1.y; v[6] = c1.z; v[7] = c1.w;
  }
#pragma unroll
  for (int s = 0; s < NS; s++) {
    const float* gr = g + s * stride + row * NC + lane * 8;
    float4 a0 = *(const float4*)gr;
    float4 a1 = *(const float4*)(gr + 4);
    v[0] += a0.x; v[1] += a0.y; v[2] += a0.z; v[3] += a0.w;
    v[4] += a1.x; v[5] += a1.y; v[6] += a1.z; v[7] += a1.w;
  }
  float s = 0.f, q = 0.f;
#pragma unroll
  for (int j = 0; j < 8; j++) { s += v[j]; q += v[j] * v[j]; }
#pragma unroll
  for (int off = 32; off > 0; off >>= 1) {
    s += __shfl_xor(s, off, 64);
    q += __shfl_xor(q, off, 64);
  }
  float mean = s * (1.f / NC);
  float var = fmaxf((q - s * s * (1.f / NC)) * (1.f / (NC - 1)), 0.f);
  float rstd = rsqrtf(var + EPSF);
  float4 w0 = *(const float4*)(gw + lane * 8), w1 = *(const float4*)(gw + lane * 8 + 4);
  float4 b0 = *(const float4*)(gb + lane * 8), b1 = *(const float4*)(gb + lane * 8 + 4);
  float gwv[8] = {w0.x, w0.y, w0.z, w0.w, w1.x, w1.y, w1.z, w1.w};
  float gbv[8] = {b0.x, b0.y, b0.z, b0.w, b1.x, b1.y, b1.z, b1.w};
  union { __hip_bfloat16 h[8]; uint4 u; } pk;
#pragma unroll
  for (int j = 0; j < 8; j++)
    pk.h[j] = __float2bfloat16(fmaxf((v[j] - mean) * rstd * gwv[j] + gbv[j], 0.f));
  *(uint4*)(out + row * NC + lane * 8) = pk.u;
}

// ---------------- fused head: sum NS mlp2 partials + bias + GELU, dot w3, sigmoid ----
template <int NS>
__global__ __launch_bounds__(256) void k_head(const float* __restrict__ g, const float* __restrict__ b2,
                                              const float* __restrict__ w3, const float* __restrict__ b3,
                                              float* __restrict__ imp) {
  __shared__ float red[4];
  int row = blockIdx.x, tid = threadIdx.x;
  int c = tid * 8;
  float v[8];
  {
    float4 x0 = *(const float4*)(b2 + c), x1 = *(const float4*)(b2 + c + 4);
    v[0] = x0.x; v[1] = x0.y; v[2] = x0.z; v[3] = x0.w;
    v[4] = x1.x; v[5] = x1.y; v[6] = x1.z; v[7] = x1.w;
  }
#pragma unroll
  for (int s = 0; s < NS; s++) {
    const float* gr = g + (size_t)s * (2048 * DM) + (size_t)row * DM + c;
    float4 a0 = *(const float4*)gr;
    float4 a1 = *(const float4*)(gr + 4);
    v[0] += a0.x; v[1] += a0.y; v[2] += a0.z; v[3] += a0.w;
    v[4] += a1.x; v[5] += a1.y; v[6] += a1.z; v[7] += a1.w;
  }
  float a = 0.f;
  float4 w0 = *(const float4*)(w3 + c), w1 = *(const float4*)(w3 + c + 4);
  float wv[8] = {w0.x, w0.y, w0.z, w0.w, w1.x, w1.y, w1.z, w1.w};
#pragma unroll
  for (int j = 0; j < 8; j++) {
    float z = 0.5f * v[j] * (1.f + erff(v[j] * 0.70710678118654752f));
    a += z * wv[j];
  }
#pragma unroll
  for (int off = 32; off > 0; off >>= 1) a += __shfl_down(a, off, 64);
  int lane = tid & 63, wid = tid >> 6;
  if (lane == 0) red[wid] = a;
  __syncthreads();
  if (tid == 0) {
    float s = red[0] + red[1] + red[2] + red[3] + b3[0];
    imp[row] = 1.f / (1.f + expf(-s)) + TEMPF;
  }
}

__device__ __forceinline__ float dfun(float cv, int n) {
  float d = fmaxf(cv - (float)n, 0.f);
  if (n < TN - 1) d = fminf(d, 1.f);
  return d;
}

// ---------------- fused cumsum + pool + final ChannelNorm + ReLU, write [B][C][TN] ----
__global__ __launch_bounds__(512) void k_poolfinal(const __hip_bfloat16* __restrict__ f,
                                                   const float* __restrict__ imp,
                                                   const float* __restrict__ gw, const float* __restrict__ gb,
                                                   float* __restrict__ out) {
  __shared__ float wt[T3];
  __shared__ float wsum[8];
  __shared__ float red[16];
  int b = blockIdx.x / TN, n = blockIdx.x % TN;
  int tid = threadIdx.x, wave = tid >> 6, lane = tid & 63;
  float own = imp[b * T3 + tid];
  float s = own;
#pragma unroll
  for (int off = 1; off < 64; off <<= 1) {
    float t = __shfl_up(s, off, 64);
    if (lane >= off) s += t;
  }
  if (lane == 63) wsum[wave] = s;
  __syncthreads();
  float prefix = 0.f, total = 0.f;
#pragma unroll
  for (int w = 0; w < 8; w++) {
    float ws_ = wsum[w];
    total += ws_;
    if (w < wave) prefix += ws_;
  }
  float scale = (float)TN / total;
  float incl = (prefix + s) * scale;
  float excl = (prefix + s - own) * scale;
  wt[tid] = dfun(incl, n) - dfun(excl, n);
  __syncthreads();
  float acc = 0.f;
  for (int t = 0; t < T3; t++) {
    float w = wt[t];
    if (w != 0.f) acc += w * __bfloat162float(f[((size_t)b * T3 + t) * NC + tid]);
  }
  float sv = acc, q = acc * acc;
  blk_sum2_512(sv, q, red);
  float mean = sv * (1.f / NC);
  float var = fmaxf((q - sv * sv * (1.f / NC)) * (1.f / (NC - 1)), 0.f);
  float y = (acc - mean) * rsqrtf(var + EPSF) * gw[tid] + gb[tid];
  out[((size_t)b * NC + tid) * TN + n] = fmaxf(y, 0.f);
}

extern "C" void kernel_launch(void* const* d_in, const int* in_sizes, int n_in,
                              void* d_out, int out_size, void* d_ws, size_t ws_size,
                              hipStream_t stream) {
  const float* x   = (const float*)d_in[0];
  const float* c0w = (const float*)d_in[1];  const float* c0b = (const float*)d_in[2];
  const float* c1w = (const float*)d_in[3];  const float* c1b = (const float*)d_in[4];
  const float* c2w = (const float*)d_in[5];  const float* c2b = (const float*)d_in[6];
  const float* c3w = (const float*)d_in[7];  const float* c3b = (const float*)d_in[8];
  const float* mw1 = (const float*)d_in[9];  const float* mb1 = (const float*)d_in[10];
  const float* mw2 = (const float*)d_in[11]; const float* mb2 = (const float*)d_in[12];
  const float* mw3 = (const float*)d_in[13]; const float* mb3 = (const float*)d_in[14];
  const float* n0w = (const float*)d_in[15]; const float* n0b = (const float*)d_in[16];
  const float* n1w = (const float*)d_in[17]; const float* n1b = (const float*)d_in[18];
  const float* n2w = (const float*)d_in[19]; const float* n2b = (const float*)d_in[20];
  const float* n3w = (const float*)d_in[21]; const float* n3b = (const float*)d_in[22];
  const float* n4w = (const float*)d_in[23]; const float* n4b = (const float*)d_in[24];

  char* base = (char*)d_ws;
  // Workspace map (MiB). Peak 94 MiB (< 97 MiB demonstrated in prior rounds).
  __hip_bfloat16* h0b  = (__hip_bfloat16*)(base);                     // [0,32): conv0 out; dead after conv1-gemm
  __hip_bfloat16* h1b  = (__hip_bfloat16*)(base);                     // reuse [0,8)
  __hip_bfloat16* h2b  = (__hip_bfloat16*)(base + (8u << 20));        // reuse [8,12)
  __hip_bfloat16* h3b  = (__hip_bfloat16*)(base + (12u << 20));       // reuse [12,14)
  __hip_bfloat16* z1b  = (__hip_bfloat16*)(base + (14u << 20));       // reuse [14,22)
  float*          imp  = (float*)(base + (22u << 20));                // reuse [22,+8K)
  float*          g    = (float*)(base + (32u << 20));                // [32,80): fp32 split-K partials (48 MiB)
  __hip_bfloat16* wm1t = (__hip_bfloat16*)(base + (80u << 20));       // [80,82)
  __hip_bfloat16* wt2  = (__hip_bfloat16*)(base + (82u << 20));       // [82,84)
  __hip_bfloat16* wt3  = (__hip_bfloat16*)(base + (84u << 20));       // [84,86)
  __hip_bfloat16* wt1  = (__hip_bfloat16*)(base + (86u << 20));       // [86,90); dead after conv1-gemm
  __hip_bfloat16* wm2t = (__hip_bfloat16*)(base + (86u << 20));       // [86,94): written AFTER conv1-gemm
  float* outp = (float*)d_out;

  k_prepA<<<2560, 256, 0, stream>>>(c1w, c2w, c3w, mw1, wt1, wt2, wt3, wm1t);
  k_conv0<<<NB * (T0 / 8), 512, 0, stream>>>(x, c0w, c0b, n0w, n0b, h0b);

  // conv1: M=8192, K=4096, N=512, SK3 -> 768 blocks (3/CU)
  k_gemm2<1, 8192, 2048, 4, 2, 4096, 512, 3, 8192><<<768, 256, 0, stream>>>(h0b, wt1, g);
  k_prepB<<<4096, 256, 0, stream>>>(mw2, wm2t);  // wt1 dead now; wm2t overwrites it
  k_cnorm<3><<<8192 / 8, 512, 0, stream>>>(g, c1b, n1w, n1b, h1b, (size_t)8192 * 512);
  // conv2: M=4096, K=2048, SK6 -> 768 blocks
  k_gemm2<1, 2048, 1024, 2, 1, 2048, 512, 6, 4096><<<768, 256, 0, stream>>>(h1b, wt2, g);
  k_cnorm<6><<<4096 / 8, 512, 0, stream>>>(g, c2b, n2w, n2b, h2b, (size_t)4096 * 512);
  // conv3: M=2048, K=2048, 64x128 tiles, SK6 -> 768 blocks
  k_gemm<1, 1024, 512, 2, 1, 2048, 512, 0, 6, 2048><<<768, 256, 0, stream>>>(h2b, wt3, nullptr, g, nullptr);
  k_cnorm<6><<<2048 / 8, 512, 0, stream>>>(g, c3b, n3w, n3b, h3b, (size_t)2048 * 512);

  // mlp1: M=2048, K=512, N=2048, EPI=GELU -> 512 blocks
  k_gemm<0, 0, 1, 0, 0, 512, 2048, 1, 1, 2048><<<512, 256, 0, stream>>>(h3b, wm1t, mb1, nullptr, z1b);
  // mlp2: M=2048, K=2048, N=2048, SK3 -> 768 blocks; head consumes fp32 partials directly
  k_gemm2<0, 0, 1, 0, 0, 2048, 2048, 3, 2048><<<768, 256, 0, stream>>>(z1b, wm2t, g);

  k_head<3><<<NB * T3, 256, 0, stream>>>(g, mb2, mw3, mb3, imp);
  k_poolfinal<<<NB * TN, 512, 0, stream>>>(h3b, imp, n4w, n4b, outp);
}

// Round 7
// 341.504 us; speedup vs baseline: 8.0886x; 1.0067x over previous
//
#include <hip/hip_runtime.h>
#include <hip/hip_bf16.h>
#include <math.h>

#define NB 4
#define LIN 40960
#define NC 512
#define T0 8192
#define T1 2048
#define T2 1024
#define T3 512
#define TN 256
#define DM 2048
#define EPSF 1e-5f
#define TEMPF 1e-5f

typedef __attribute__((ext_vector_type(8))) short bf16x8;
typedef __attribute__((ext_vector_type(4))) float f32x4;

__device__ __forceinline__ int refl(int t, int T) {
  if (t < 0) t = -t;
  if (t >= T) t = 2 * T - 2 - t;
  return t;
}

__device__ __forceinline__ void gld16(void* lds, const void* g) {
  __builtin_amdgcn_global_load_lds((const __attribute__((address_space(1))) unsigned int*)g,
                                   (__attribute__((address_space(3))) unsigned int*)lds, 16, 0, 0);
}

__device__ __forceinline__ void blk_sum2_512(float& a, float& b, float* scratch) {
#pragma unroll
  for (int off = 32; off > 0; off >>= 1) {
    a += __shfl_down(a, off, 64);
    b += __shfl_down(b, off, 64);
  }
  int lane = threadIdx.x & 63, wid = threadIdx.x >> 6;
  __syncthreads();
  if (lane == 0) { scratch[wid] = a; scratch[8 + wid] = b; }
  __syncthreads();
  float sa = 0.f, sb = 0.f;
#pragma unroll
  for (int i = 0; i < 8; i++) { sa += scratch[i]; sb += scratch[8 + i]; }
  a = sa; b = sb;
}

// load 8 bf16 (16B) -> 8 floats, accumulate
__device__ __forceinline__ void add_bf8(const __hip_bfloat16* p, float* v) {
  union { uint4 u; __hip_bfloat16 h[8]; } pk;
  pk.u = *(const uint4*)p;
#pragma unroll
  for (int j = 0; j < 8; j++) v[j] += __bfloat162float(pk.h[j]);
}

// ---------------- weight prep (single kernel) ----------------
template <int KT>
__device__ __forceinline__ void prep_conv_body(const float* __restrict__ w, __hip_bfloat16* __restrict__ wt,
                                               int co, float* l) {
  const float* wb = w + (size_t)co * 512 * KT;
  for (int i = threadIdx.x; i < 512 * KT; i += 256) l[i] = wb[i];
  __syncthreads();
  __hip_bfloat16* wo = wt + (size_t)co * 512 * KT;
  for (int i = threadIdx.x; i < 512 * KT; i += 256) {
    int kk = i >> 9, ci = i & 511;
    wo[i] = __float2bfloat16(l[ci * KT + kk]);
  }
}

template <int KD, int ND>
__device__ __forceinline__ void prep_mlp_body(const float* __restrict__ w, __hip_bfloat16* __restrict__ wt,
                                              int bidx, float* sbuf) {
  float(*tile)[33] = (float(*)[33])sbuf;
  int bx = bidx % (ND / 32);
  int by = bidx / (ND / 32);
  int tx = threadIdx.x & 31, ty = threadIdx.x >> 5;
#pragma unroll
  for (int i = 0; i < 32; i += 8)
    tile[ty + i][tx] = w[(size_t)(by * 32 + ty + i) * ND + bx * 32 + tx];
  __syncthreads();
#pragma unroll
  for (int i = 0; i < 32; i += 8)
    wt[(size_t)(bx * 32 + ty + i) * KD + by * 32 + tx] = __float2bfloat16(tile[tx][ty + i]);
}

// 512+512+512+1024+4096 = 6656 blocks
__global__ __launch_bounds__(256) void k_prep(const float* c1w, const float* c2w, const float* c3w,
                                              const float* mw1, const float* mw2,
                                              __hip_bfloat16* wt1, __hip_bfloat16* wt2,
                                              __hip_bfloat16* wt3, __hip_bfloat16* wm1t,
                                              __hip_bfloat16* wm2t) {
  __shared__ float sb[4096];
  int b = blockIdx.x;
  if (b < 512) prep_conv_body<8>(c1w, wt1, b, sb);
  else if (b < 1024) prep_conv_body<4>(c2w, wt2, b - 512, sb);
  else if (b < 1536) prep_conv_body<4>(c3w, wt3, b - 1024, sb);
  else if (b < 2560) prep_mlp_body<512, 2048>(mw1, wm1t, b - 1536, sb);
  else prep_mlp_body<2048, 2048>(mw2, wm2t, b - 2560, sb);
}

// ---------------- conv0 + ChannelNorm + ReLU -> bf16 ----------------
__global__ __launch_bounds__(512) void k_conv0(const float* __restrict__ x, const float* __restrict__ w,
                                               const float* __restrict__ bias, const float* __restrict__ gw,
                                               const float* __restrict__ gb, __hip_bfloat16* __restrict__ out) {
  __shared__ float xv[48];
  __shared__ float tb[512 * 9];
  __shared__ float stats[16];
  int b = blockIdx.x / (T0 / 8);
  int t0 = (blockIdx.x % (T0 / 8)) * 8;
  int tid = threadIdx.x;
  if (tid < 45) xv[tid] = x[(size_t)b * LIN + refl(t0 * 5 - 3 + tid, LIN)];
  __syncthreads();
  float wk[10];
#pragma unroll
  for (int k = 0; k < 10; k++) wk[k] = w[tid * 10 + k];
  float bs = bias[tid];
  float acc[8];
#pragma unroll
  for (int tt = 0; tt < 8; tt++) {
    float a = bs;
#pragma unroll
    for (int k = 0; k < 10; k++) a += xv[tt * 5 + k] * wk[k];
    acc[tt] = a;
    tb[tid * 9 + tt] = a;
  }
  __syncthreads();
  int wave = tid >> 6, lane = tid & 63;
  float s = 0.f, q = 0.f;
#pragma unroll
  for (int j = 0; j < 8; j++) {
    float v = tb[(lane * 8 + j) * 9 + wave];
    s += v; q += v * v;
  }
#pragma unroll
  for (int off = 32; off > 0; off >>= 1) {
    s += __shfl_xor(s, off, 64);
    q += __shfl_xor(q, off, 64);
  }
  if (lane == 0) {
    float mean = s * (1.f / NC);
    float var = fmaxf((q - s * s * (1.f / NC)) * (1.f / (NC - 1)), 0.f);
    stats[wave] = mean;
    stats[8 + wave] = rsqrtf(var + EPSF);
  }
  __syncthreads();
  float gwv = gw[tid], gbv = gb[tid];
#pragma unroll
  for (int tt = 0; tt < 8; tt++) {
    float y = (acc[tt] - stats[tt]) * stats[8 + tt] * gwv + gbv;
    out[((size_t)(b * T0 + t0 + tt)) * NC + tid] = __float2bfloat16(fmaxf(y, 0.f));
  }
}

// ---------------- MFMA GEMM v2: 128x128 tile, BK=32, dbuf, split-K, bf16 partials ----
template <int MODE, int TIN_, int TOUT_, int SS, int PP, int KK, int NN, int SPLITK, int MM>
__global__ __launch_bounds__(256) void k_gemm2(const __hip_bfloat16* __restrict__ A,
                                               const __hip_bfloat16* __restrict__ Bt,
                                               __hip_bfloat16* __restrict__ Cp) {
  __shared__ __align__(16) __hip_bfloat16 sA[2][128 * 32];
  __shared__ __align__(16) __hip_bfloat16 sB[2][128 * 32];
  const int tid = threadIdx.x;
  const int lane = tid & 63;
  const int wave = tid >> 6;
  const int wm = wave >> 1, wn = wave & 1;
  constexpr int nt = NN / 128;
  constexpr int PS = (MM / 1024) * nt;
  constexpr int KBT = KK / 32;
  const int blk = blockIdx.x;
  const int xs = blk & 7, sl = blk >> 3;
  const int sk = sl / PS, rem = sl % PS;
  const int row0 = ((rem / nt) * 8 + xs) * 128;
  const int col0 = (rem % nt) * 128;
  const int kb0 = (sk * KBT) / SPLITK, kb1 = ((sk + 1) * KBT) / SPLITK;
  const int cq = lane >> 4, cl = lane & 15;

  auto stage = [&](int kb, int buf) {
#pragma unroll
    for (int rr = 0; rr < 2; rr++) {
      int c = rr * 256 + tid;
      int m = c >> 2, kc = c & 3;
      int kcs = kc ^ (m & 3);
      size_t ga;
      if (MODE == 0) {
        ga = (size_t)(row0 + m) * KK + kb * 32 + kcs * 8;
      } else {
        int r = row0 + m;
        int bb = r / TOUT_;
        int t = r - bb * TOUT_;
        int k = (kb * 32) >> 9;
        int ci = ((kb * 32) & 511) + kcs * 8;
        int gt = refl(t * SS - PP + k, TIN_);
        ga = (((size_t)(bb * TIN_ + gt)) << 9) + ci;
      }
      gld16((char*)&sA[buf][0] + c * 16, (const char*)(A + ga));
    }
#pragma unroll
    for (int rr = 0; rr < 2; rr++) {
      int c = rr * 256 + tid;
      int n = c >> 2, kc = c & 3;
      int kcs = kc ^ (n & 3);
      gld16((char*)&sB[buf][0] + c * 16, (const char*)(Bt + (size_t)(col0 + n) * KK + kb * 32 + kcs * 8));
    }
  };

  f32x4 acc[4][4];
  const f32x4 zz = {0.f, 0.f, 0.f, 0.f};
#pragma unroll
  for (int mi = 0; mi < 4; mi++)
#pragma unroll
    for (int ni = 0; ni < 4; ni++) acc[mi][ni] = zz;

  stage(kb0, 0);
  const int p = cq ^ (cl & 3);
  for (int kb = kb0; kb < kb1; kb++) {
    int cur = (kb - kb0) & 1;
    __syncthreads();
    if (kb + 1 < kb1) stage(kb + 1, cur ^ 1);
    const short* bA = (const short*)&sA[cur][0];
    const short* bB = (const short*)&sB[cur][0];
    bf16x8 af[4], bfr[4];
#pragma unroll
    for (int mi = 0; mi < 4; mi++)
      af[mi] = *(const bf16x8*)(bA + (wm * 64 + mi * 16 + cl) * 32 + p * 8);
#pragma unroll
    for (int ni = 0; ni < 4; ni++)
      bfr[ni] = *(const bf16x8*)(bB + (wn * 64 + ni * 16 + cl) * 32 + p * 8);
#pragma unroll
    for (int mi = 0; mi < 4; mi++)
#pragma unroll
      for (int ni = 0; ni < 4; ni++)
        acc[mi][ni] = __builtin_amdgcn_mfma_f32_16x16x32_bf16(af[mi], bfr[ni], acc[mi][ni], 0, 0, 0);
  }

  // C/D: col=lane&15, row=(lane>>4)*4+reg; bf16 partial out
#pragma unroll
  for (int mi = 0; mi < 4; mi++)
#pragma unroll
    for (int ni = 0; ni < 4; ni++)
#pragma unroll
      for (int r2 = 0; r2 < 4; r2++) {
        int row = row0 + wm * 64 + mi * 16 + cq * 4 + r2;
        int col = col0 + wn * 64 + ni * 16 + cl;
        Cp[(size_t)sk * MM * NN + (size_t)row * NN + col] = __float2bfloat16(acc[mi][ni][r2]);
      }
}

// ---------------- MFMA GEMM v1: 64x128 tile (conv3, mlp1) ----------
// EPI 0: bf16 partial to Cout + sk*MM*NN. EPI 1: +bias, exact GELU -> bf16 Cout.
template <int MODE, int TIN_, int TOUT_, int SS, int PP, int KK, int NN, int EPI, int SPLITK, int MM>
__global__ __launch_bounds__(256) void k_gemm(const __hip_bfloat16* __restrict__ A,
                                              const __hip_bfloat16* __restrict__ Bt,
                                              const float* __restrict__ bias,
                                              __hip_bfloat16* __restrict__ Cout) {
  __shared__ __align__(16) __hip_bfloat16 sA[2][64 * 32];
  __shared__ __align__(16) __hip_bfloat16 sB[2][128 * 32];
  const int tid = threadIdx.x;
  const int lane = tid & 63;
  const int wave = tid >> 6;
  const int wm = wave >> 1, wn = wave & 1;
  constexpr int nt = NN / 128;
  constexpr int PS = (MM / 512) * nt;
  constexpr int KBT = KK / 32;
  const int blk = blockIdx.x;
  const int xs = blk & 7, sl = blk >> 3;
  const int sk = sl / PS, rem = sl % PS;
  const int row0 = ((rem / nt) * 8 + xs) * 64;
  const int col0 = (rem % nt) * 128;
  const int kb0 = (sk * KBT) / SPLITK, kb1 = ((sk + 1) * KBT) / SPLITK;
  const int cq = lane >> 4, cl = lane & 15;

  auto stage = [&](int kb, int buf) {
    {
      int m = tid >> 2, kc = tid & 3;
      int kcs = kc ^ (m & 3);
      size_t ga;
      if (MODE == 0) {
        ga = (size_t)(row0 + m) * KK + kb * 32 + kcs * 8;
      } else {
        int r = row0 + m;
        int bb = r / TOUT_;
        int t = r - bb * TOUT_;
        int k = (kb * 32) >> 9;
        int ci = ((kb * 32) & 511) + kcs * 8;
        int gt = refl(t * SS - PP + k, TIN_);
        ga = (((size_t)(bb * TIN_ + gt)) << 9) + ci;
      }
      gld16((char*)&sA[buf][0] + tid * 16, (const char*)(A + ga));
    }
#pragma unroll
    for (int rr = 0; rr < 2; rr++) {
      int c = rr * 256 + tid;
      int n = c >> 2, kc = c & 3;
      int kcs = kc ^ (n & 3);
      gld16((char*)&sB[buf][0] + c * 16, (const char*)(Bt + (size_t)(col0 + n) * KK + kb * 32 + kcs * 8));
    }
  };

  f32x4 acc[2][4];
  const f32x4 zz = {0.f, 0.f, 0.f, 0.f};
#pragma unroll
  for (int mi = 0; mi < 2; mi++)
#pragma unroll
    for (int ni = 0; ni < 4; ni++) acc[mi][ni] = zz;

  stage(kb0, 0);
  const int p = cq ^ (cl & 3);
  for (int kb = kb0; kb < kb1; kb++) {
    int cur = (kb - kb0) & 1;
    __syncthreads();
    if (kb + 1 < kb1) stage(kb + 1, cur ^ 1);
    const short* bA = (const short*)&sA[cur][0];
    const short* bB = (const short*)&sB[cur][0];
    bf16x8 af[2], bfr[4];
#pragma unroll
    for (int mi = 0; mi < 2; mi++)
      af[mi] = *(const bf16x8*)(bA + (wm * 32 + mi * 16 + cl) * 32 + p * 8);
#pragma unroll
    for (int ni = 0; ni < 4; ni++)
      bfr[ni] = *(const bf16x8*)(bB + (wn * 64 + ni * 16 + cl) * 32 + p * 8);
#pragma unroll
    for (int mi = 0; mi < 2; mi++)
#pragma unroll
      for (int ni = 0; ni < 4; ni++)
        acc[mi][ni] = __builtin_amdgcn_mfma_f32_16x16x32_bf16(af[mi], bfr[ni], acc[mi][ni], 0, 0, 0);
  }

#pragma unroll
  for (int mi = 0; mi < 2; mi++)
#pragma unroll
    for (int ni = 0; ni < 4; ni++)
#pragma unroll
      for (int r2 = 0; r2 < 4; r2++) {
        int row = row0 + wm * 32 + mi * 16 + cq * 4 + r2;
        int col = col0 + wn * 64 + ni * 16 + cl;
        float v = acc[mi][ni][r2];
        if (EPI == 1) {
          v += bias[col];
          v = 0.5f * v * (1.f + erff(v * 0.70710678118654752f));
          Cout[(size_t)row * NN + col] = __float2bfloat16(v);
        } else {
          Cout[(size_t)sk * MM * NN + (size_t)row * NN + col] = __float2bfloat16(v);
        }
      }
}

// ---------------- ChannelNorm (+conv bias, sum NS bf16 split-K partials) + ReLU -> bf16
template <int NS>
__global__ __launch_bounds__(512) void k_cnorm(const __hip_bfloat16* __restrict__ g,
                                               const float* __restrict__ cb,
                                               const float* __restrict__ gw, const float* __restrict__ gb,
                                               __hip_bfloat16* __restrict__ out, size_t stride) {
  int wave = threadIdx.x >> 6, lane = threadIdx.x & 63;
  size_t row = (size_t)blockIdx.x * 8 + wave;
  float v[8];
  {
    float4 c0 = *(const float4*)(cb + lane * 8), c1 = *(const float4*)(cb + lane * 8 + 4);
    v[0] = c0.x; v[1] = c0.y; v[2] = c0.z; v[3] = c0.w;
    v[4] = c1.x; v[5] = c1.y; v[6] = c1.z; v[7] = c1.w;
  }
#pragma unroll
  for (int s = 0; s < NS; s++) add_bf8(g + s * stride + row * NC + lane * 8, v);
  float s = 0.f, q = 0.f;
#pragma unroll
  for (int j = 0; j < 8; j++) { s += v[j]; q += v[j] * v[j]; }
#pragma unroll
  for (int off = 32; off > 0; off >>= 1) {
    s += __shfl_xor(s, off, 64);
    q += __shfl_xor(q, off, 64);
  }
  float mean = s * (1.f / NC);
  float var = fmaxf((q - s * s * (1.f / NC)) * (1.f / (NC - 1)), 0.f);
  float rstd = rsqrtf(var + EPSF);
  float4 w0 = *(const float4*)(gw + lane * 8), w1 = *(const float4*)(gw + lane * 8 + 4);
  float4 b0 = *(const float4*)(gb + lane * 8), b1 = *(const float4*)(gb + lane * 8 + 4);
  float gwv[8] = {w0.x, w0.y, w0.z, w0.w, w1.x, w1.y, w1.z, w1.w};
  float gbv[8] = {b0.x, b0.y, b0.z, b0.w, b1.x, b1.y, b1.z, b1.w};
  union { __hip_bfloat16 h[8]; uint4 u; } pk;
#pragma unroll
  for (int j = 0; j < 8; j++)
    pk.h[j] = __float2bfloat16(fmaxf((v[j] - mean) * rstd * gwv[j] + gbv[j], 0.f));
  *(uint4*)(out + row * NC + lane * 8) = pk.u;
}

// ---------------- fused head: sum NS bf16 partials + bias + GELU, dot w3, sigmoid ----
template <int NS>
__global__ __launch_bounds__(256) void k_head(const __hip_bfloat16* __restrict__ g,
                                              const float* __restrict__ b2,
                                              const float* __restrict__ w3, const float* __restrict__ b3,
                                              float* __restrict__ imp) {
  __shared__ float red[4];
  int row = blockIdx.x, tid = threadIdx.x;
  int c = tid * 8;
  float v[8];
  {
    float4 x0 = *(const float4*)(b2 + c), x1 = *(const float4*)(b2 + c + 4);
    v[0] = x0.x; v[1] = x0.y; v[2] = x0.z; v[3] = x0.w;
    v[4] = x1.x; v[5] = x1.y; v[6] = x1.z; v[7] = x1.w;
  }
#pragma unroll
  for (int s = 0; s < NS; s++) add_bf8(g + (size_t)s * (2048 * DM) + (size_t)row * DM + c, v);
  float a = 0.f;
  float4 w0 = *(const float4*)(w3 + c), w1 = *(const float4*)(w3 + c + 4);
  float wv[8] = {w0.x, w0.y, w0.z, w0.w, w1.x, w1.y, w1.z, w1.w};
#pragma unroll
  for (int j = 0; j < 8; j++) {
    float z = 0.5f * v[j] * (1.f + erff(v[j] * 0.70710678118654752f));
    a += z * wv[j];
  }
#pragma unroll
  for (int off = 32; off > 0; off >>= 1) a += __shfl_down(a, off, 64);
  int lane = tid & 63, wid = tid >> 6;
  if (lane == 0) red[wid] = a;
  __syncthreads();
  if (tid == 0) {
    float s = red[0] + red[1] + red[2] + red[3] + b3[0];
    imp[row] = 1.f / (1.f + expf(-s)) + TEMPF;
  }
}

__device__ __forceinline__ float dfun(float cv, int n) {
  float d = fmaxf(cv - (float)n, 0.f);
  if (n < TN - 1) d = fminf(d, 1.f);
  return d;
}

// ---------------- fused cumsum + pool + final ChannelNorm + ReLU, write [B][C][TN] ----
__global__ __launch_bounds__(512) void k_poolfinal(const __hip_bfloat16* __restrict__ f,
                                                   const float* __restrict__ imp,
                                                   const float* __restrict__ gw, const float* __restrict__ gb,
                                                   float* __restrict__ out) {
  __shared__ float wt[T3];
  __shared__ float wsum[8];
  __shared__ float red[16];
  int b = blockIdx.x / TN, n = blockIdx.x % TN;
  int tid = threadIdx.x, wave = tid >> 6, lane = tid & 63;
  float own = imp[b * T3 + tid];
  float s = own;
#pragma unroll
  for (int off = 1; off < 64; off <<= 1) {
    float t = __shfl_up(s, off, 64);
    if (lane >= off) s += t;
  }
  if (lane == 63) wsum[wave] = s;
  __syncthreads();
  float prefix = 0.f, total = 0.f;
#pragma unroll
  for (int w = 0; w < 8; w++) {
    float ws_ = wsum[w];
    total += ws_;
    if (w < wave) prefix += ws_;
  }
  float scale = (float)TN / total;
  float incl = (prefix + s) * scale;
  float excl = (prefix + s - own) * scale;
  wt[tid] = dfun(incl, n) - dfun(excl, n);
  __syncthreads();
  float acc = 0.f;
  for (int t = 0; t < T3; t++) {
    float w = wt[t];
    if (w != 0.f) acc += w * __bfloat162float(f[((size_t)b * T3 + t) * NC + tid]);
  }
  float sv = acc, q = acc * acc;
  blk_sum2_512(sv, q, red);
  float mean = sv * (1.f / NC);
  float var = fmaxf((q - sv * sv * (1.f / NC)) * (1.f / (NC - 1)), 0.f);
  float y = (acc - mean) * rsqrtf(var + EPSF) * gw[tid] + gb[tid];
  out[((size_t)b * NC + tid) * TN + n] = fmaxf(y, 0.f);
}

extern "C" void kernel_launch(void* const* d_in, const int* in_sizes, int n_in,
                              void* d_out, int out_size, void* d_ws, size_t ws_size,
                              hipStream_t stream) {
  const float* x   = (const float*)d_in[0];
  const float* c0w = (const float*)d_in[1];  const float* c0b = (const float*)d_in[2];
  const float* c1w = (const float*)d_in[3];  const float* c1b = (const float*)d_in[4];
  const float* c2w = (const float*)d_in[5];  const float* c2b = (const float*)d_in[6];
  const float* c3w = (const float*)d_in[7];  const float* c3b = (const float*)d_in[8];
  const float* mw1 = (const float*)d_in[9];  const float* mb1 = (const float*)d_in[10];
  const float* mw2 = (const float*)d_in[11]; const float* mb2 = (const float*)d_in[12];
  const float* mw3 = (const float*)d_in[13]; const float* mb3 = (const float*)d_in[14];
  const float* n0w = (const float*)d_in[15]; const float* n0b = (const float*)d_in[16];
  const float* n1w = (const float*)d_in[17]; const float* n1b = (const float*)d_in[18];
  const float* n2w = (const float*)d_in[19]; const float* n2b = (const float*)d_in[20];
  const float* n3w = (const float*)d_in[21]; const float* n3b = (const float*)d_in[22];
  const float* n4w = (const float*)d_in[23]; const float* n4b = (const float*)d_in[24];

  char* base = (char*)d_ws;
  // Workspace map (MiB). Peak 82 MiB.
  __hip_bfloat16* h0b  = (__hip_bfloat16*)(base);                     // [0,32): conv0 out; dead after conv1-gemm
  __hip_bfloat16* h1b  = (__hip_bfloat16*)(base);                     // reuse [0,8)
  __hip_bfloat16* h2b  = (__hip_bfloat16*)(base + (8u << 20));        // reuse [8,12)
  __hip_bfloat16* h3b  = (__hip_bfloat16*)(base + (12u << 20));       // reuse [12,14)
  __hip_bfloat16* z1b  = (__hip_bfloat16*)(base + (14u << 20));       // reuse [14,22)
  float*          imp  = (float*)(base + (22u << 20));                // reuse [22,+8K)
  __hip_bfloat16* g    = (__hip_bfloat16*)(base + (32u << 20));       // [32,64): bf16 split-K partials
  __hip_bfloat16* wm1t = (__hip_bfloat16*)(base + (64u << 20));       // [64,66)
  __hip_bfloat16* wt2  = (__hip_bfloat16*)(base + (66u << 20));       // [66,68)
  __hip_bfloat16* wt3  = (__hip_bfloat16*)(base + (68u << 20));       // [68,70)
  __hip_bfloat16* wt1  = (__hip_bfloat16*)(base + (70u << 20));       // [70,74)
  __hip_bfloat16* wm2t = (__hip_bfloat16*)(base + (74u << 20));       // [74,82)
  float* outp = (float*)d_out;

  k_prep<<<6656, 256, 0, stream>>>(c1w, c2w, c3w, mw1, mw2, wt1, wt2, wt3, wm1t, wm2t);
  k_conv0<<<NB * (T0 / 8), 512, 0, stream>>>(x, c0w, c0b, n0w, n0b, h0b);

  // conv1: M=8192, K=4096, N=512, SK4 -> 1024 blocks (4/CU)
  k_gemm2<1, 8192, 2048, 4, 2, 4096, 512, 4, 8192><<<1024, 256, 0, stream>>>(h0b, wt1, g);
  k_cnorm<4><<<8192 / 8, 512, 0, stream>>>(g, c1b, n1w, n1b, h1b, (size_t)8192 * 512);
  // conv2: M=4096, K=2048, SK8 -> 1024 blocks
  k_gemm2<1, 2048, 1024, 2, 1, 2048, 512, 8, 4096><<<1024, 256, 0, stream>>>(h1b, wt2, g);
  k_cnorm<8><<<4096 / 8, 512, 0, stream>>>(g, c2b, n2w, n2b, h2b, (size_t)4096 * 512);
  // conv3: M=2048, K=2048, 64x128 tiles, SK8 -> 1024 blocks
  k_gemm<1, 1024, 512, 2, 1, 2048, 512, 0, 8, 2048><<<1024, 256, 0, stream>>>(h2b, wt3, nullptr, g);
  k_cnorm<8><<<2048 / 8, 512, 0, stream>>>(g, c3b, n3w, n3b, h3b, (size_t)2048 * 512);

  // mlp1: M=2048, K=512, N=2048, EPI=GELU -> 512 blocks
  k_gemm<0, 0, 1, 0, 0, 512, 2048, 1, 1, 2048><<<512, 256, 0, stream>>>(h3b, wm1t, mb1, z1b);
  // mlp2: M=2048, K=2048, N=2048, SK4 -> 1024 blocks; head consumes bf16 partials
  k_gemm2<0, 0, 1, 0, 0, 2048, 2048, 4, 2048><<<1024, 256, 0, stream>>>(z1b, wm2t, g);

  k_head<4><<<NB * T3, 256, 0, stream>>>(g, mb2, mw3, mb3, imp);
  k_poolfinal<<<NB * TN, 512, 0, stream>>>(h3b, imp, n4w, n4b, outp);
}

// Round 8
// 321.589 us; speedup vs baseline: 8.5895x; 1.0619x over previous
//
#include <hip/hip_runtime.h>
#include <hip/hip_bf16.h>
#include <math.h>

#define NB 4
#define LIN 40960
#define NC 512
#define T0 8192
#define T1 2048
#define T2 1024
#define T3 512
#define TN 256
#define DM 2048
#define EPSF 1e-5f
#define TEMPF 1e-5f

typedef __attribute__((ext_vector_type(8))) short bf16x8;
typedef __attribute__((ext_vector_type(4))) float f32x4;

__device__ __forceinline__ int refl(int t, int T) {
  if (t < 0) t = -t;
  if (t >= T) t = 2 * T - 2 - t;
  return t;
}

__device__ __forceinline__ void gld16(void* lds, const void* g) {
  __builtin_amdgcn_global_load_lds((const __attribute__((address_space(1))) unsigned int*)g,
                                   (__attribute__((address_space(3))) unsigned int*)lds, 16, 0, 0);
}

__device__ __forceinline__ void blk_sum2_512(float& a, float& b, float* scratch) {
#pragma unroll
  for (int off = 32; off > 0; off >>= 1) {
    a += __shfl_down(a, off, 64);
    b += __shfl_down(b, off, 64);
  }
  int lane = threadIdx.x & 63, wid = threadIdx.x >> 6;
  __syncthreads();
  if (lane == 0) { scratch[wid] = a; scratch[8 + wid] = b; }
  __syncthreads();
  float sa = 0.f, sb = 0.f;
#pragma unroll
  for (int i = 0; i < 8; i++) { sa += scratch[i]; sb += scratch[8 + i]; }
  a = sa; b = sb;
}

// load 8 bf16 (16B) -> 8 floats, accumulate
__device__ __forceinline__ void add_bf8(const __hip_bfloat16* p, float* v) {
  union { uint4 u; __hip_bfloat16 h[8]; } pk;
  pk.u = *(const uint4*)p;
#pragma unroll
  for (int j = 0; j < 8; j++) v[j] += __bfloat162float(pk.h[j]);
}

// ---------------- weight prep (single kernel) ----------------
template <int KT>
__device__ __forceinline__ void prep_conv_body(const float* __restrict__ w, __hip_bfloat16* __restrict__ wt,
                                               int co, float* l) {
  const float* wb = w + (size_t)co * 512 * KT;
  for (int i = threadIdx.x; i < 512 * KT; i += 256) l[i] = wb[i];
  __syncthreads();
  __hip_bfloat16* wo = wt + (size_t)co * 512 * KT;
  for (int i = threadIdx.x; i < 512 * KT; i += 256) {
    int kk = i >> 9, ci = i & 511;
    wo[i] = __float2bfloat16(l[ci * KT + kk]);
  }
}

template <int KD, int ND>
__device__ __forceinline__ void prep_mlp_body(const float* __restrict__ w, __hip_bfloat16* __restrict__ wt,
                                              int bidx, float* sbuf) {
  float(*tile)[33] = (float(*)[33])sbuf;
  int bx = bidx % (ND / 32);
  int by = bidx / (ND / 32);
  int tx = threadIdx.x & 31, ty = threadIdx.x >> 5;
#pragma unroll
  for (int i = 0; i < 32; i += 8)
    tile[ty + i][tx] = w[(size_t)(by * 32 + ty + i) * ND + bx * 32 + tx];
  __syncthreads();
#pragma unroll
  for (int i = 0; i < 32; i += 8)
    wt[(size_t)(bx * 32 + ty + i) * KD + by * 32 + tx] = __float2bfloat16(tile[tx][ty + i]);
}

// 512+512+512+1024+4096 = 6656 blocks
__global__ __launch_bounds__(256) void k_prep(const float* c1w, const float* c2w, const float* c3w,
                                              const float* mw1, const float* mw2,
                                              __hip_bfloat16* wt1, __hip_bfloat16* wt2,
                                              __hip_bfloat16* wt3, __hip_bfloat16* wm1t,
                                              __hip_bfloat16* wm2t) {
  __shared__ float sb[4096];
  int b = blockIdx.x;
  if (b < 512) prep_conv_body<8>(c1w, wt1, b, sb);
  else if (b < 1024) prep_conv_body<4>(c2w, wt2, b - 512, sb);
  else if (b < 1536) prep_conv_body<4>(c3w, wt3, b - 1024, sb);
  else if (b < 2560) prep_mlp_body<512, 2048>(mw1, wm1t, b - 1536, sb);
  else prep_mlp_body<2048, 2048>(mw2, wm2t, b - 2560, sb);
}

// ---------------- conv0 + ChannelNorm + ReLU -> bf16 ----------------
__global__ __launch_bounds__(512) void k_conv0(const float* __restrict__ x, const float* __restrict__ w,
                                               const float* __restrict__ bias, const float* __restrict__ gw,
                                               const float* __restrict__ gb, __hip_bfloat16* __restrict__ out) {
  __shared__ float xv[48];
  __shared__ float tb[512 * 9];
  __shared__ float stats[16];
  int b = blockIdx.x / (T0 / 8);
  int t0 = (blockIdx.x % (T0 / 8)) * 8;
  int tid = threadIdx.x;
  if (tid < 45) xv[tid] = x[(size_t)b * LIN + refl(t0 * 5 - 3 + tid, LIN)];
  __syncthreads();
  float wk[10];
#pragma unroll
  for (int k = 0; k < 10; k++) wk[k] = w[tid * 10 + k];
  float bs = bias[tid];
  float acc[8];
#pragma unroll
  for (int tt = 0; tt < 8; tt++) {
    float a = bs;
#pragma unroll
    for (int k = 0; k < 10; k++) a += xv[tt * 5 + k] * wk[k];
    acc[tt] = a;
    tb[tid * 9 + tt] = a;
  }
  __syncthreads();
  int wave = tid >> 6, lane = tid & 63;
  float s = 0.f, q = 0.f;
#pragma unroll
  for (int j = 0; j < 8; j++) {
    float v = tb[(lane * 8 + j) * 9 + wave];
    s += v; q += v * v;
  }
#pragma unroll
  for (int off = 32; off > 0; off >>= 1) {
    s += __shfl_xor(s, off, 64);
    q += __shfl_xor(q, off, 64);
  }
  if (lane == 0) {
    float mean = s * (1.f / NC);
    float var = fmaxf((q - s * s * (1.f / NC)) * (1.f / (NC - 1)), 0.f);
    stats[wave] = mean;
    stats[8 + wave] = rsqrtf(var + EPSF);
  }
  __syncthreads();
  float gwv = gw[tid], gbv = gb[tid];
#pragma unroll
  for (int tt = 0; tt < 8; tt++) {
    float y = (acc[tt] - stats[tt]) * stats[8 + tt] * gwv + gbv;
    out[((size_t)(b * T0 + t0 + tt)) * NC + tid] = __float2bfloat16(fmaxf(y, 0.f));
  }
}

// ---------------- MFMA GEMM v2: 128x128 tile, BK=32, dbuf, split-K, bf16 partials ----
// Residency note: VGPR ~72 + 64 AGPR -> 3 waves/SIMD -> grids must be 768 (3 blocks/CU).
template <int MODE, int TIN_, int TOUT_, int SS, int PP, int KK, int NN, int SPLITK, int MM>
__global__ __launch_bounds__(256) void k_gemm2(const __hip_bfloat16* __restrict__ A,
                                               const __hip_bfloat16* __restrict__ Bt,
                                               __hip_bfloat16* __restrict__ Cp) {
  __shared__ __align__(16) __hip_bfloat16 sA[2][128 * 32];
  __shared__ __align__(16) __hip_bfloat16 sB[2][128 * 32];
  const int tid = threadIdx.x;
  const int lane = tid & 63;
  const int wave = tid >> 6;
  const int wm = wave >> 1, wn = wave & 1;
  constexpr int nt = NN / 128;
  constexpr int PS = (MM / 1024) * nt;
  constexpr int KBT = KK / 32;
  const int blk = blockIdx.x;
  const int xs = blk & 7, sl = blk >> 3;
  const int sk = sl / PS, rem = sl % PS;
  const int row0 = ((rem / nt) * 8 + xs) * 128;
  const int col0 = (rem % nt) * 128;
  const int kb0 = (sk * KBT) / SPLITK, kb1 = ((sk + 1) * KBT) / SPLITK;
  const int cq = lane >> 4, cl = lane & 15;

  auto stage = [&](int kb, int buf) {
#pragma unroll
    for (int rr = 0; rr < 2; rr++) {
      int c = rr * 256 + tid;
      int m = c >> 2, kc = c & 3;
      int kcs = kc ^ (m & 3);
      size_t ga;
      if (MODE == 0) {
        ga = (size_t)(row0 + m) * KK + kb * 32 + kcs * 8;
      } else {
        int r = row0 + m;
        int bb = r / TOUT_;
        int t = r - bb * TOUT_;
        int k = (kb * 32) >> 9;
        int ci = ((kb * 32) & 511) + kcs * 8;
        int gt = refl(t * SS - PP + k, TIN_);
        ga = (((size_t)(bb * TIN_ + gt)) << 9) + ci;
      }
      gld16((char*)&sA[buf][0] + c * 16, (const char*)(A + ga));
    }
#pragma unroll
    for (int rr = 0; rr < 2; rr++) {
      int c = rr * 256 + tid;
      int n = c >> 2, kc = c & 3;
      int kcs = kc ^ (n & 3);
      gld16((char*)&sB[buf][0] + c * 16, (const char*)(Bt + (size_t)(col0 + n) * KK + kb * 32 + kcs * 8));
    }
  };

  f32x4 acc[4][4];
  const f32x4 zz = {0.f, 0.f, 0.f, 0.f};
#pragma unroll
  for (int mi = 0; mi < 4; mi++)
#pragma unroll
    for (int ni = 0; ni < 4; ni++) acc[mi][ni] = zz;

  stage(kb0, 0);
  const int p = cq ^ (cl & 3);
  for (int kb = kb0; kb < kb1; kb++) {
    int cur = (kb - kb0) & 1;
    __syncthreads();
    if (kb + 1 < kb1) stage(kb + 1, cur ^ 1);
    const short* bA = (const short*)&sA[cur][0];
    const short* bB = (const short*)&sB[cur][0];
    bf16x8 af[4], bfr[4];
#pragma unroll
    for (int mi = 0; mi < 4; mi++)
      af[mi] = *(const bf16x8*)(bA + (wm * 64 + mi * 16 + cl) * 32 + p * 8);
#pragma unroll
    for (int ni = 0; ni < 4; ni++)
      bfr[ni] = *(const bf16x8*)(bB + (wn * 64 + ni * 16 + cl) * 32 + p * 8);
#pragma unroll
    for (int mi = 0; mi < 4; mi++)
#pragma unroll
      for (int ni = 0; ni < 4; ni++)
        acc[mi][ni] = __builtin_amdgcn_mfma_f32_16x16x32_bf16(af[mi], bfr[ni], acc[mi][ni], 0, 0, 0);
  }

  // C/D: col=lane&15, row=(lane>>4)*4+reg; bf16 partial out
#pragma unroll
  for (int mi = 0; mi < 4; mi++)
#pragma unroll
    for (int ni = 0; ni < 4; ni++)
#pragma unroll
      for (int r2 = 0; r2 < 4; r2++) {
        int row = row0 + wm * 64 + mi * 16 + cq * 4 + r2;
        int col = col0 + wn * 64 + ni * 16 + cl;
        Cp[(size_t)sk * MM * NN + (size_t)row * NN + col] = __float2bfloat16(acc[mi][ni][r2]);
      }
}

// ---------------- MFMA GEMM v1: 64x128 tile (conv3, mlp1) ----------
// EPI 0: bf16 partial to Cout + sk*MM*NN. EPI 1: +bias, exact GELU -> bf16 Cout.
template <int MODE, int TIN_, int TOUT_, int SS, int PP, int KK, int NN, int EPI, int SPLITK, int MM>
__global__ __launch_bounds__(256) void k_gemm(const __hip_bfloat16* __restrict__ A,
                                              const __hip_bfloat16* __restrict__ Bt,
                                              const float* __restrict__ bias,
                                              __hip_bfloat16* __restrict__ Cout) {
  __shared__ __align__(16) __hip_bfloat16 sA[2][64 * 32];
  __shared__ __align__(16) __hip_bfloat16 sB[2][128 * 32];
  const int tid = threadIdx.x;
  const int lane = tid & 63;
  const int wave = tid >> 6;
  const int wm = wave >> 1, wn = wave & 1;
  constexpr int nt = NN / 128;
  constexpr int PS = (MM / 512) * nt;
  constexpr int KBT = KK / 32;
  const int blk = blockIdx.x;
  const int xs = blk & 7, sl = blk >> 3;
  const int sk = sl / PS, rem = sl % PS;
  const int row0 = ((rem / nt) * 8 + xs) * 64;
  const int col0 = (rem % nt) * 128;
  const int kb0 = (sk * KBT) / SPLITK, kb1 = ((sk + 1) * KBT) / SPLITK;
  const int cq = lane >> 4, cl = lane & 15;

  auto stage = [&](int kb, int buf) {
    {
      int m = tid >> 2, kc = tid & 3;
      int kcs = kc ^ (m & 3);
      size_t ga;
      if (MODE == 0) {
        ga = (size_t)(row0 + m) * KK + kb * 32 + kcs * 8;
      } else {
        int r = row0 + m;
        int bb = r / TOUT_;
        int t = r - bb * TOUT_;
        int k = (kb * 32) >> 9;
        int ci = ((kb * 32) & 511) + kcs * 8;
        int gt = refl(t * SS - PP + k, TIN_);
        ga = (((size_t)(bb * TIN_ + gt)) << 9) + ci;
      }
      gld16((char*)&sA[buf][0] + tid * 16, (const char*)(A + ga));
    }
#pragma unroll
    for (int rr = 0; rr < 2; rr++) {
      int c = rr * 256 + tid;
      int n = c >> 2, kc = c & 3;
      int kcs = kc ^ (n & 3);
      gld16((char*)&sB[buf][0] + c * 16, (const char*)(Bt + (size_t)(col0 + n) * KK + kb * 32 + kcs * 8));
    }
  };

  f32x4 acc[2][4];
  const f32x4 zz = {0.f, 0.f, 0.f, 0.f};
#pragma unroll
  for (int mi = 0; mi < 2; mi++)
#pragma unroll
    for (int ni = 0; ni < 4; ni++) acc[mi][ni] = zz;

  stage(kb0, 0);
  const int p = cq ^ (cl & 3);
  for (int kb = kb0; kb < kb1; kb++) {
    int cur = (kb - kb0) & 1;
    __syncthreads();
    if (kb + 1 < kb1) stage(kb + 1, cur ^ 1);
    const short* bA = (const short*)&sA[cur][0];
    const short* bB = (const short*)&sB[cur][0];
    bf16x8 af[2], bfr[4];
#pragma unroll
    for (int mi = 0; mi < 2; mi++)
      af[mi] = *(const bf16x8*)(bA + (wm * 32 + mi * 16 + cl) * 32 + p * 8);
#pragma unroll
    for (int ni = 0; ni < 4; ni++)
      bfr[ni] = *(const bf16x8*)(bB + (wn * 64 + ni * 16 + cl) * 32 + p * 8);
#pragma unroll
    for (int mi = 0; mi < 2; mi++)
#pragma unroll
      for (int ni = 0; ni < 4; ni++)
        acc[mi][ni] = __builtin_amdgcn_mfma_f32_16x16x32_bf16(af[mi], bfr[ni], acc[mi][ni], 0, 0, 0);
  }

#pragma unroll
  for (int mi = 0; mi < 2; mi++)
#pragma unroll
    for (int ni = 0; ni < 4; ni++)
#pragma unroll
      for (int r2 = 0; r2 < 4; r2++) {
        int row = row0 + wm * 32 + mi * 16 + cq * 4 + r2;
        int col = col0 + wn * 64 + ni * 16 + cl;
        float v = acc[mi][ni][r2];
        if (EPI == 1) {
          v += bias[col];
          v = 0.5f * v * (1.f + erff(v * 0.70710678118654752f));
          Cout[(size_t)row * NN + col] = __float2bfloat16(v);
        } else {
          Cout[(size_t)sk * MM * NN + (size_t)row * NN + col] = __float2bfloat16(v);
        }
      }
}

// ---------------- ChannelNorm (+conv bias, sum NS bf16 split-K partials) + ReLU -> bf16
template <int NS>
__global__ __launch_bounds__(512) void k_cnorm(const __hip_bfloat16* __restrict__ g,
                                               const float* __restrict__ cb,
                                               const float* __restrict__ gw, const float* __restrict__ gb,
                                               __hip_bfloat16* __restrict__ out, size_t stride) {
  int wave = threadIdx.x >> 6, lane = threadIdx.x & 63;
  size_t row = (size_t)blockIdx.x * 8 + wave;
  float v[8];
  {
    float4 c0 = *(const float4*)(cb + lane * 8), c1 = *(const float4*)(cb + lane * 8 + 4);
    v[0] = c0.x; v[1] = c0.y; v[2] = c0.z; v[3] = c0.w;
    v[4] = c1.x; v[5] = c1.y; v[6] = c1.z; v[7] = c1.w;
  }
#pragma unroll
  for (int s = 0; s < NS; s++) add_bf8(g + s * stride + row * NC + lane * 8, v);
  float s = 0.f, q = 0.f;
#pragma unroll
  for (int j = 0; j < 8; j++) { s += v[j]; q += v[j] * v[j]; }
#pragma unroll
  for (int off = 32; off > 0; off >>= 1) {
    s += __shfl_xor(s, off, 64);
    q += __shfl_xor(q, off, 64);
  }
  float mean = s * (1.f / NC);
  float var = fmaxf((q - s * s * (1.f / NC)) * (1.f / (NC - 1)), 0.f);
  float rstd = rsqrtf(var + EPSF);
  float4 w0 = *(const float4*)(gw + lane * 8), w1 = *(const float4*)(gw + lane * 8 + 4);
  float4 b0 = *(const float4*)(gb + lane * 8), b1 = *(const float4*)(gb + lane * 8 + 4);
  float gwv[8] = {w0.x, w0.y, w0.z, w0.w, w1.x, w1.y, w1.z, w1.w};
  float gbv[8] = {b0.x, b0.y, b0.z, b0.w, b1.x, b1.y, b1.z, b1.w};
  union { __hip_bfloat16 h[8]; uint4 u; } pk;
#pragma unroll
  for (int j = 0; j < 8; j++)
    pk.h[j] = __float2bfloat16(fmaxf((v[j] - mean) * rstd * gwv[j] + gbv[j], 0.f));
  *(uint4*)(out + row * NC + lane * 8) = pk.u;
}

// ---------------- fused head: sum NS bf16 partials + bias + GELU, dot w3, sigmoid ----
template <int NS>
__global__ __launch_bounds__(256) void k_head(const __hip_bfloat16* __restrict__ g,
                                              const float* __restrict__ b2,
                                              const float* __restrict__ w3, const float* __restrict__ b3,
                                              float* __restrict__ imp) {
  __shared__ float red[4];
  int row = blockIdx.x, tid = threadIdx.x;
  int c = tid * 8;
  float v[8];
  {
    float4 x0 = *(const float4*)(b2 + c), x1 = *(const float4*)(b2 + c + 4);
    v[0] = x0.x; v[1] = x0.y; v[2] = x0.z; v[3] = x0.w;
    v[4] = x1.x; v[5] = x1.y; v[6] = x1.z; v[7] = x1.w;
  }
#pragma unroll
  for (int s = 0; s < NS; s++) add_bf8(g + (size_t)s * (2048 * DM) + (size_t)row * DM + c, v);
  float a = 0.f;
  float4 w0 = *(const float4*)(w3 + c), w1 = *(const float4*)(w3 + c + 4);
  float wv[8] = {w0.x, w0.y, w0.z, w0.w, w1.x, w1.y, w1.z, w1.w};
#pragma unroll
  for (int j = 0; j < 8; j++) {
    float z = 0.5f * v[j] * (1.f + erff(v[j] * 0.70710678118654752f));
    a += z * wv[j];
  }
#pragma unroll
  for (int off = 32; off > 0; off >>= 1) a += __shfl_down(a, off, 64);
  int lane = tid & 63, wid = tid >> 6;
  if (lane == 0) red[wid] = a;
  __syncthreads();
  if (tid == 0) {
    float s = red[0] + red[1] + red[2] + red[3] + b3[0];
    imp[row] = 1.f / (1.f + expf(-s)) + TEMPF;
  }
}

__device__ __forceinline__ float dfun(float cv, int n) {
  float d = fmaxf(cv - (float)n, 0.f);
  if (n < TN - 1) d = fminf(d, 1.f);
  return d;
}

// ---------------- fused cumsum + pool + final ChannelNorm + ReLU, write [B][C][TN] ----
__global__ __launch_bounds__(512) void k_poolfinal(const __hip_bfloat16* __restrict__ f,
                                                   const float* __restrict__ imp,
                                                   const float* __restrict__ gw, const float* __restrict__ gb,
                                                   float* __restrict__ out) {
  __shared__ float wt[T3];
  __shared__ float wsum[8];
  __shared__ float red[16];
  int b = blockIdx.x / TN, n = blockIdx.x % TN;
  int tid = threadIdx.x, wave = tid >> 6, lane = tid & 63;
  float own = imp[b * T3 + tid];
  float s = own;
#pragma unroll
  for (int off = 1; off < 64; off <<= 1) {
    float t = __shfl_up(s, off, 64);
    if (lane >= off) s += t;
  }
  if (lane == 63) wsum[wave] = s;
  __syncthreads();
  float prefix = 0.f, total = 0.f;
#pragma unroll
  for (int w = 0; w < 8; w++) {
    float ws_ = wsum[w];
    total += ws_;
    if (w < wave) prefix += ws_;
  }
  float scale = (float)TN / total;
  float incl = (prefix + s) * scale;
  float excl = (prefix + s - own) * scale;
  wt[tid] = dfun(incl, n) - dfun(excl, n);
  __syncthreads();
  float acc = 0.f;
  for (int t = 0; t < T3; t++) {
    float w = wt[t];
    if (w != 0.f) acc += w * __bfloat162float(f[((size_t)b * T3 + t) * NC + tid]);
  }
  float sv = acc, q = acc * acc;
  blk_sum2_512(sv, q, red);
  float mean = sv * (1.f / NC);
  float var = fmaxf((q - sv * sv * (1.f / NC)) * (1.f / (NC - 1)), 0.f);
  float y = (acc - mean) * rsqrtf(var + EPSF) * gw[tid] + gb[tid];
  out[((size_t)b * NC + tid) * TN + n] = fmaxf(y, 0.f);
}

extern "C" void kernel_launch(void* const* d_in, const int* in_sizes, int n_in,
                              void* d_out, int out_size, void* d_ws, size_t ws_size,
                              hipStream_t stream) {
  const float* x   = (const float*)d_in[0];
  const float* c0w = (const float*)d_in[1];  const float* c0b = (const float*)d_in[2];
  const float* c1w = (const float*)d_in[3];  const float* c1b = (const float*)d_in[4];
  const float* c2w = (const float*)d_in[5];  const float* c2b = (const float*)d_in[6];
  const float* c3w = (const float*)d_in[7];  const float* c3b = (const float*)d_in[8];
  const float* mw1 = (const float*)d_in[9];  const float* mb1 = (const float*)d_in[10];
  const float* mw2 = (const float*)d_in[11]; const float* mb2 = (const float*)d_in[12];
  const float* mw3 = (const float*)d_in[13]; const float* mb3 = (const float*)d_in[14];
  const float* n0w = (const float*)d_in[15]; const float* n0b = (const float*)d_in[16];
  const float* n1w = (const float*)d_in[17]; const float* n1b = (const float*)d_in[18];
  const float* n2w = (const float*)d_in[19]; const float* n2b = (const float*)d_in[20];
  const float* n3w = (const float*)d_in[21]; const float* n3b = (const float*)d_in[22];
  const float* n4w = (const float*)d_in[23]; const float* n4b = (const float*)d_in[24];

  char* base = (char*)d_ws;
  // Workspace map (MiB). Peak 82 MiB.
  __hip_bfloat16* h0b  = (__hip_bfloat16*)(base);                     // [0,32): conv0 out; dead after conv1-gemm
  __hip_bfloat16* h1b  = (__hip_bfloat16*)(base);                     // reuse [0,8)
  __hip_bfloat16* h2b  = (__hip_bfloat16*)(base + (8u << 20));        // reuse [8,12)
  __hip_bfloat16* h3b  = (__hip_bfloat16*)(base + (12u << 20));       // reuse [12,14)
  __hip_bfloat16* z1b  = (__hip_bfloat16*)(base + (14u << 20));       // reuse [14,22)
  float*          imp  = (float*)(base + (22u << 20));                // reuse [22,+8K)
  __hip_bfloat16* g    = (__hip_bfloat16*)(base + (32u << 20));       // [32,64): bf16 split-K partials
  __hip_bfloat16* wm1t = (__hip_bfloat16*)(base + (64u << 20));       // [64,66)
  __hip_bfloat16* wt2  = (__hip_bfloat16*)(base + (66u << 20));       // [66,68)
  __hip_bfloat16* wt3  = (__hip_bfloat16*)(base + (68u << 20));       // [68,70)
  __hip_bfloat16* wt1  = (__hip_bfloat16*)(base + (70u << 20));       // [70,74)
  __hip_bfloat16* wm2t = (__hip_bfloat16*)(base + (74u << 20));       // [74,82)
  float* outp = (float*)d_out;

  k_prep<<<6656, 256, 0, stream>>>(c1w, c2w, c3w, mw1, mw2, wt1, wt2, wt3, wm1t, wm2t);
  k_conv0<<<NB * (T0 / 8), 512, 0, stream>>>(x, c0w, c0b, n0w, n0b, h0b);

  // conv1: M=8192, K=4096, N=512, SK3 -> 768 blocks (3/CU, matches 136-reg residency)
  k_gemm2<1, 8192, 2048, 4, 2, 4096, 512, 3, 8192><<<768, 256, 0, stream>>>(h0b, wt1, g);
  k_cnorm<3><<<8192 / 8, 512, 0, stream>>>(g, c1b, n1w, n1b, h1b, (size_t)8192 * 512);
  // conv2: M=4096, K=2048, SK6 -> 768 blocks
  k_gemm2<1, 2048, 1024, 2, 1, 2048, 512, 6, 4096><<<768, 256, 0, stream>>>(h1b, wt2, g);
  k_cnorm<6><<<4096 / 8, 512, 0, stream>>>(g, c2b, n2w, n2b, h2b, (size_t)4096 * 512);
  // conv3: M=2048, K=2048, 64x128 tiles, SK6 -> 768 blocks
  k_gemm<1, 1024, 512, 2, 1, 2048, 512, 0, 6, 2048><<<768, 256, 0, stream>>>(h2b, wt3, nullptr, g);
  k_cnorm<6><<<2048 / 8, 512, 0, stream>>>(g, c3b, n3w, n3b, h3b, (size_t)2048 * 512);

  // mlp1: M=2048, K=512, N=2048, EPI=GELU -> 512 blocks
  k_gemm<0, 0, 1, 0, 0, 512, 2048, 1, 1, 2048><<<512, 256, 0, stream>>>(h3b, wm1t, mb1, z1b);
  // mlp2: M=2048, K=2048, N=2048, SK3 -> 768 blocks; head consumes bf16 partials
  k_gemm2<0, 0, 1, 0, 0, 2048, 2048, 3, 2048><<<768, 256, 0, stream>>>(z1b, wm2t, g);

  k_head<3><<<NB * T3, 256, 0, stream>>>(g, mb2, mw3, mb3, imp);
  k_poolfinal<<<NB * TN, 512, 0, stream>>>(h3b, imp, n4w, n4b, outp);
}